// Round 2
// baseline (963.963 us; speedup 1.0000x reference)
//
#include <hip/hip_runtime.h>

typedef unsigned short u16;
typedef __attribute__((ext_vector_type(8))) short short8;
typedef __attribute__((ext_vector_type(4))) float floatx4;

#define DEVI static __device__ __forceinline__

DEVI float bf2f(u16 u) {
  union { unsigned u; float f; } x; x.u = ((unsigned)u) << 16; return x.f;
}
DEVI u16 f2bf(float f) {
  union { float f; unsigned u; } x; x.f = f;
  unsigned r = x.u + 0x7fffu + ((x.u >> 16) & 1u);  // RNE
  return (u16)(r >> 16);
}

#define BM 128
#define BN 128
#define BK 32

// mode 0: C = hidden(f32) @ W_qkv(f32,[K][N]) + b_qkv -> scatter bf16 Q(scaled), K, Vt
// mode 1: S = Q @ K^T per head (bf16, B is [N][K]); skip fully-masked blocks
// mode 2: ctx = P @ Vt^T per head (bf16, B is [N][K]); causal K-limit
// mode 3: out(f32) = ctx(bf16) @ W_dense(f32,[K][N]) + b_dense
__global__ __launch_bounds__(256)
void gemm_kernel(const void* __restrict__ Av, const void* __restrict__ Bv,
                 int K, int lda, int ldb,
                 long sAz, long sBz, int mode, int head0,
                 const float* __restrict__ bias,
                 u16* __restrict__ out0, u16* __restrict__ out1,
                 u16* __restrict__ out2, float* __restrict__ outf)
{
  const int bn = blockIdx.x, bm = blockIdx.y, z = blockIdx.z;
  const int m0 = bm * BM, n0 = bn * BN;
  if (mode == 1 && n0 > m0 + (BM - 1)) return;      // fully above diagonal
  int kEnd = K;
  if (mode == 2) { int ke = m0 + BM; kEnd = ke < K ? ke : K; }

  const bool aF32 = (mode == 0);
  const bool bF32 = (mode == 0 || mode == 3);       // B fp32, layout [K][N]
  const float* Af = (const float*)Av;
  const u16*   Ab = (const u16*)Av + (long)z * sAz;
  const float* Bf = (const float*)Bv;
  const u16*   Bb = (const u16*)Bv + (long)z * sBz;

  __shared__ __align__(16) u16 As[BM * BK];   // [m][k] bf16
  __shared__ __align__(16) u16 Bs[BN * BK];   // [n][k] bf16

  const int tid  = threadIdx.x;
  const int lane = tid & 63;
  const int wave = tid >> 6;
  const int wm   = (wave & 1) * 64;
  const int wn   = (wave >> 1) * 64;
  const int lr   = lane & 15;
  const int quad = lane >> 4;

  floatx4 acc[4][4];
  #pragma unroll
  for (int i = 0; i < 4; i++)
    #pragma unroll
    for (int j = 0; j < 4; j++)
      acc[i][j] = floatx4{0.f, 0.f, 0.f, 0.f};

  for (int k0 = 0; k0 < kEnd; k0 += BK) {
    __syncthreads();   // protect LDS from previous iteration's readers
    // ---- stage A tile: 128x32 -> bf16 [m][k]
    if (aF32) {
      #pragma unroll
      for (int L = tid; L < 1024; L += 256) {
        int row = L >> 3, c4 = (L & 7) * 4;
        float4 v = *(const float4*)(Af + (long)(m0 + row) * lda + k0 + c4);
        ushort4 p;
        p.x = f2bf(v.x); p.y = f2bf(v.y); p.z = f2bf(v.z); p.w = f2bf(v.w);
        *(ushort4*)(&As[row * BK + c4]) = p;
      }
    } else {
      #pragma unroll
      for (int L = tid; L < 512; L += 256) {
        int row = L >> 2, c8 = (L & 3) * 8;
        uint4 v = *(const uint4*)(Ab + (long)(m0 + row) * lda + k0 + c8);
        *(uint4*)(&As[row * BK + c8]) = v;
      }
    }
    // ---- stage B tile -> bf16 [n][k]
    if (bF32) {
      // B is fp32 [K][N]: vector-load along N, transpose into Bs[n][k]
      #pragma unroll
      for (int L = tid; L < 1024; L += 256) {
        int kr = L >> 5, n4 = (L & 31) * 4;
        float4 v = *(const float4*)(Bf + (long)(k0 + kr) * ldb + n0 + n4);
        Bs[(n4 + 0) * BK + kr] = f2bf(v.x);
        Bs[(n4 + 1) * BK + kr] = f2bf(v.y);
        Bs[(n4 + 2) * BK + kr] = f2bf(v.z);
        Bs[(n4 + 3) * BK + kr] = f2bf(v.w);
      }
    } else {
      // B already bf16 [N][K]: direct vectorized copy
      #pragma unroll
      for (int L = tid; L < 512; L += 256) {
        int row = L >> 2, c8 = (L & 3) * 8;
        uint4 v = *(const uint4*)(Bb + (long)(n0 + row) * ldb + k0 + c8);
        *(uint4*)(&Bs[row * BK + c8]) = v;
      }
    }
    __syncthreads();

    short8 af[4], bf[4];
    #pragma unroll
    for (int i = 0; i < 4; i++)
      af[i] = *(const short8*)(&As[(wm + i * 16 + lr) * BK + quad * 8]);
    #pragma unroll
    for (int j = 0; j < 4; j++)
      bf[j] = *(const short8*)(&Bs[(wn + j * 16 + lr) * BK + quad * 8]);
    #pragma unroll
    for (int i = 0; i < 4; i++)
      #pragma unroll
      for (int j = 0; j < 4; j++)
        acc[i][j] = __builtin_amdgcn_mfma_f32_16x16x32_bf16(af[i], bf[j], acc[i][j], 0, 0, 0);
  }

  // epilogue: C/D layout col=lane&15, row=quad*4+reg
  #pragma unroll
  for (int i = 0; i < 4; i++) {
    #pragma unroll
    for (int j = 0; j < 4; j++) {
      #pragma unroll
      for (int r = 0; r < 4; r++) {
        int row = m0 + wm + i * 16 + quad * 4 + r;
        int col = n0 + wn + j * 16 + lr;
        float v = acc[i][j][r];
        if (mode == 0) {
          v += bias[col];
          int head = col / 384;
          int w = col - head * 384;
          long hbase = (long)head * 2048 * 128;
          if (w < 128) {        // Q, pre-scaled by 1/sqrt(128)
            out0[hbase + (long)row * 128 + w] = f2bf(v * 0.08838834764831845f);
          } else if (w < 256) { // K
            out1[hbase + (long)row * 128 + (w - 128)] = f2bf(v);
          } else {              // V -> Vt[head][d][t]
            out2[hbase + (long)(w - 256) * 2048 + row] = f2bf(v);
          }
        } else if (mode == 1) {
          out0[((long)z * 2048 + row) * 2048 + col] = f2bf(v);
        } else if (mode == 2) {
          out0[(long)row * 2048 + (head0 + z) * 128 + col] = f2bf(v);
        } else {
          outf[(long)row * 2048 + col] = v + bias[col];
        }
      }
    }
  }
}

// RoPE in-place on first 32 dims of Q and K (bf16 ws). rot=32, half=16.
// out[d]   = x[d]*cos - x[d+16]*sin ; out[d+16] = x[d+16]*cos + x[d]*sin
__global__ __launch_bounds__(256)
void rope_kernel(u16* __restrict__ Q, u16* __restrict__ K)
{
  int idx = blockIdx.x * 256 + threadIdx.x;   // 2 * 16 * 2048 * 16 = 1048576
  int i = idx & 15;
  int s = (idx >> 4) & 2047;
  int head = (idx >> 15) & 15;
  u16* buf = (idx >> 19) ? K : Q;
  long base = ((long)head * 2048 + s) * 128;
  // inv_freq = 10000^(-i/16) = 2^(-i * log2(10000)/16)
  float inv_freq = exp2f(-(float)i * 0.83048202372184058696f);
  float ang = (float)s * inv_freq;
  float c = cosf(ang), sn = sinf(ang);
  float x1 = bf2f(buf[base + i]);
  float x2 = bf2f(buf[base + i + 16]);
  buf[base + i]      = f2bf(x1 * c - x2 * sn);
  buf[base + i + 16] = f2bf(x2 * c + x1 * sn);
}

// causal softmax over row [0..row], zeros above the diagonal; in-place bf16
__global__ __launch_bounds__(256)
void softmax_kernel(u16* __restrict__ SP)
{
  int row = blockIdx.x;
  int z = blockIdx.y;
  u16* p = SP + ((long)z * 2048 + row) * 2048;
  int n = row + 1;
  int tid = threadIdx.x;
  __shared__ float red[256];

  float vals[8];
  float m = -1e30f;
  #pragma unroll
  for (int j = 0; j < 8; j++) {
    int t = tid + j * 256;
    vals[j] = (t < n) ? bf2f(p[t]) : -1e30f;
    m = fmaxf(m, vals[j]);
  }
  red[tid] = m; __syncthreads();
  for (int s = 128; s > 0; s >>= 1) {
    if (tid < s) red[tid] = fmaxf(red[tid], red[tid + s]);
    __syncthreads();
  }
  m = red[0];
  __syncthreads();

  float sum = 0.f;
  #pragma unroll
  for (int j = 0; j < 8; j++) {
    int t = tid + j * 256;
    float e = (t < n) ? __expf(vals[j] - m) : 0.f;
    vals[j] = e;
    sum += e;
  }
  red[tid] = sum; __syncthreads();
  for (int s = 128; s > 0; s >>= 1) {
    if (tid < s) red[tid] += red[tid + s];
    __syncthreads();
  }
  float inv = 1.f / red[0];
  #pragma unroll
  for (int j = 0; j < 8; j++) {
    int t = tid + j * 256;
    p[t] = f2bf(vals[j] * inv);   // masked lanes write 0
  }
}

extern "C" void kernel_launch(void* const* d_in, const int* in_sizes, int n_in,
                              void* d_out, int out_size, void* d_ws, size_t ws_size,
                              hipStream_t stream)
{
  const float* hidden = (const float*)d_in[0];   // [2048][2048] f32
  const float* Wqkv   = (const float*)d_in[1];   // [2048][6144] f32
  const float* bqkv   = (const float*)d_in[2];   // [6144] f32
  const float* Wd     = (const float*)d_in[3];   // [2048][2048] f32
  const float* bd     = (const float*)d_in[4];   // [2048] f32
  float* out = (float*)d_out;                    // [2048][2048] f32

  char* ws = (char*)d_ws;
  u16* Q   = (u16*)(ws);                      //  8 MB  [16][2048][128] bf16
  u16* Kb  = (u16*)(ws + (8ull  << 20));      //  8 MB  [16][2048][128]
  u16* Vt  = (u16*)(ws + (16ull << 20));      //  8 MB  [16][128][2048]
  u16* ctx = (u16*)(ws + (24ull << 20));      //  8 MB  [2048][2048]
  u16* S   = (u16*)(ws + (32ull << 20));      //  8 MB per head in group

  size_t avail = ws_size > (32ull << 20) ? ws_size - (32ull << 20) : 0;
  int gh = (int)(avail / (8ull << 20));
  if (gh > 16) gh = 16;
  if (gh < 1)  gh = 1;

  const long HS = 2048L * 128;   // per-head stride for Q/K/Vt (elements)

  // 1) QKV GEMM (f32 in) + scatter bf16
  gemm_kernel<<<dim3(48, 16, 1), 256, 0, stream>>>(
      hidden, Wqkv, 2048, 2048, 6144, 0, 0, /*mode*/0, 0, bqkv,
      Q, Kb, Vt, nullptr);

  // 2) RoPE on Q and K
  rope_kernel<<<dim3(4096), 256, 0, stream>>>(Q, Kb);

  // 3) attention, per head group sized by ws
  for (int h0 = 0; h0 < 16; h0 += gh) {
    int g = 16 - h0 < gh ? 16 - h0 : gh;
    gemm_kernel<<<dim3(16, 16, g), 256, 0, stream>>>(
        Q + h0 * HS, Kb + h0 * HS, 128, 128, 128, HS, HS,
        /*mode*/1, h0, nullptr, S, nullptr, nullptr, nullptr);
    softmax_kernel<<<dim3(2048, g), 256, 0, stream>>>(S);
    gemm_kernel<<<dim3(1, 16, g), 256, 0, stream>>>(
        S, Vt + h0 * HS, 2048, 2048, 2048, 2048L * 2048, HS,
        /*mode*/2, h0, nullptr, ctx, nullptr, nullptr, nullptr);
  }

  // 4) dense GEMM (bf16 A, f32 B) + bias -> f32 out
  gemm_kernel<<<dim3(16, 16, 1), 256, 0, stream>>>(
      ctx, Wd, 2048, 2048, 2048, 0, 0, /*mode*/3, 0, bd,
      nullptr, nullptr, nullptr, out);
}

// Round 3
// 787.465 us; speedup vs baseline: 1.2241x; 1.2241x over previous
//
#include <hip/hip_runtime.h>

typedef unsigned short u16;
typedef __attribute__((ext_vector_type(8))) short short8;
typedef __attribute__((ext_vector_type(4))) float floatx4;

#define DEVI static __device__ __forceinline__

DEVI float bf2f(u16 u) {
  union { unsigned u; float f; } x; x.u = ((unsigned)u) << 16; return x.f;
}
DEVI u16 f2bf(float f) {
  union { float f; unsigned u; } x; x.f = f;
  unsigned r = x.u + 0x7fffu + ((x.u >> 16) & 1u);  // RNE
  return (u16)(r >> 16);
}

#define BM 128
#define BN 128
#define BK 32

// Epilogue modes:
// 0: QKV: +bias, scatter Q(scaled)/K/Vt as bf16
// 1: S = Q@K^T per head, causal block skip, bf16 out
// 2: ctx = P@Vt^T per head, causal K-limit, bf16 out (column slice per head)
// 3: out(f32) = ctx@Wd + bias
// aF32: A is fp32 [M][K] (convert during staging). Else A is bf16 [M][K].
// bF32: B is fp32 [K][N] (transpose+convert during staging; slow fallback).
//       Else B is bf16 [N][K] (fast path).
__global__ __launch_bounds__(256)
void gemm_kernel(const void* __restrict__ Av, const void* __restrict__ Bv,
                 int K, int lda, int ldb,
                 long sAz, long sBz, int mode, int head0, int aF32, int bF32,
                 const float* __restrict__ bias,
                 u16* __restrict__ out0, u16* __restrict__ out1,
                 u16* __restrict__ out2, float* __restrict__ outf)
{
  const int bn = blockIdx.x, bm = blockIdx.y, z = blockIdx.z;
  const int m0 = bm * BM, n0 = bn * BN;
  if (mode == 1 && n0 > m0 + (BM - 1)) return;      // fully above diagonal
  int kEnd = K;
  if (mode == 2) { int ke = m0 + BM; kEnd = ke < K ? ke : K; }

  const float* Af = (const float*)Av;
  const u16*   Ab = (const u16*)Av + (long)z * sAz;
  const float* Bf = (const float*)Bv;
  const u16*   Bb = (const u16*)Bv + (long)z * sBz;

  __shared__ __align__(16) u16 As[BM * BK];   // [m][k] bf16
  __shared__ __align__(16) u16 Bs[BN * BK];   // [n][k] bf16

  const int tid  = threadIdx.x;
  const int lane = tid & 63;
  const int wave = tid >> 6;
  const int wm   = (wave & 1) * 64;
  const int wn   = (wave >> 1) * 64;
  const int lr   = lane & 15;
  const int quad = lane >> 4;

  floatx4 acc[4][4];
  #pragma unroll
  for (int i = 0; i < 4; i++)
    #pragma unroll
    for (int j = 0; j < 4; j++)
      acc[i][j] = floatx4{0.f, 0.f, 0.f, 0.f};

  for (int k0 = 0; k0 < kEnd; k0 += BK) {
    __syncthreads();   // protect LDS from previous iteration's readers
    // ---- stage A tile: 128x32 -> bf16 [m][k]
    if (aF32) {
      #pragma unroll
      for (int L = tid; L < 1024; L += 256) {
        int row = L >> 3, c4 = (L & 7) * 4;
        float4 v = *(const float4*)(Af + (long)(m0 + row) * lda + k0 + c4);
        ushort4 p;
        p.x = f2bf(v.x); p.y = f2bf(v.y); p.z = f2bf(v.z); p.w = f2bf(v.w);
        *(ushort4*)(&As[row * BK + c4]) = p;
      }
    } else {
      #pragma unroll
      for (int L = tid; L < 512; L += 256) {
        int row = L >> 2, c8 = (L & 3) * 8;
        uint4 v = *(const uint4*)(Ab + (long)(m0 + row) * lda + k0 + c8);
        *(uint4*)(&As[row * BK + c8]) = v;
      }
    }
    // ---- stage B tile -> bf16 [n][k]
    if (bF32) {
      // fallback: B fp32 [K][N], transpose into Bs[n][k]
      #pragma unroll
      for (int L = tid; L < 1024; L += 256) {
        int kr = L >> 5, n4 = (L & 31) * 4;
        float4 v = *(const float4*)(Bf + (long)(k0 + kr) * ldb + n0 + n4);
        Bs[(n4 + 0) * BK + kr] = f2bf(v.x);
        Bs[(n4 + 1) * BK + kr] = f2bf(v.y);
        Bs[(n4 + 2) * BK + kr] = f2bf(v.z);
        Bs[(n4 + 3) * BK + kr] = f2bf(v.w);
      }
    } else {
      // fast path: B bf16 [N][K], direct vectorized copy
      #pragma unroll
      for (int L = tid; L < 512; L += 256) {
        int row = L >> 2, c8 = (L & 3) * 8;
        uint4 v = *(const uint4*)(Bb + (long)(n0 + row) * ldb + k0 + c8);
        *(uint4*)(&Bs[row * BK + c8]) = v;
      }
    }
    __syncthreads();

    short8 af[4], bf[4];
    #pragma unroll
    for (int i = 0; i < 4; i++)
      af[i] = *(const short8*)(&As[(wm + i * 16 + lr) * BK + quad * 8]);
    #pragma unroll
    for (int j = 0; j < 4; j++)
      bf[j] = *(const short8*)(&Bs[(wn + j * 16 + lr) * BK + quad * 8]);
    #pragma unroll
    for (int i = 0; i < 4; i++)
      #pragma unroll
      for (int j = 0; j < 4; j++)
        acc[i][j] = __builtin_amdgcn_mfma_f32_16x16x32_bf16(af[i], bf[j], acc[i][j], 0, 0, 0);
  }

  // epilogue: C/D layout col=lane&15, row=quad*4+reg
  #pragma unroll
  for (int i = 0; i < 4; i++) {
    #pragma unroll
    for (int j = 0; j < 4; j++) {
      #pragma unroll
      for (int r = 0; r < 4; r++) {
        int row = m0 + wm + i * 16 + quad * 4 + r;
        int col = n0 + wn + j * 16 + lr;
        float v = acc[i][j][r];
        if (mode == 0) {
          v += bias[col];
          int head = col / 384;
          int w = col - head * 384;
          long hbase = (long)head * 2048 * 128;
          if (w < 128) {        // Q, pre-scaled by 1/sqrt(128)
            out0[hbase + (long)row * 128 + w] = f2bf(v * 0.08838834764831845f);
          } else if (w < 256) { // K
            out1[hbase + (long)row * 128 + (w - 128)] = f2bf(v);
          } else {              // V -> Vt[head][d][t]
            out2[hbase + (long)(w - 256) * 2048 + row] = f2bf(v);
          }
        } else if (mode == 1) {
          out0[((long)z * 2048 + row) * 2048 + col] = f2bf(v);
        } else if (mode == 2) {
          out0[(long)row * 2048 + (head0 + z) * 128 + col] = f2bf(v);
        } else {
          outf[(long)row * 2048 + col] = v + bias[col];
        }
      }
    }
  }
}

// fp32 -> bf16 same-layout convert, float4/thread
__global__ __launch_bounds__(256)
void convert_bf16_kernel(const float* __restrict__ in, u16* __restrict__ out, long n4)
{
  long i = (long)blockIdx.x * 256 + threadIdx.x;
  if (i < n4) {
    float4 v = ((const float4*)in)[i];
    ushort4 p;
    p.x = f2bf(v.x); p.y = f2bf(v.y); p.z = f2bf(v.z); p.w = f2bf(v.w);
    ((ushort4*)out)[i] = p;
  }
}

// fp32 [K][N] -> bf16 [N][K] transpose+convert. 32x32 tiles.
__global__ __launch_bounds__(256)
void transpose_bf16_kernel(const float* __restrict__ in, u16* __restrict__ out,
                           int K, int N)
{
  __shared__ float t[32][33];
  int n0 = blockIdx.x * 32, k0 = blockIdx.y * 32;
  int tx = threadIdx.x & 31, ty = threadIdx.x >> 5;   // 32 cols x 8 rows
  #pragma unroll
  for (int i = 0; i < 4; i++)
    t[ty + i * 8][tx] = in[(long)(k0 + ty + i * 8) * N + n0 + tx];
  __syncthreads();
  #pragma unroll
  for (int i = 0; i < 4; i++)
    out[(long)(n0 + ty + i * 8) * K + k0 + tx] = f2bf(t[tx][ty + i * 8]);
}

// RoPE in-place on first 32 dims of Q and K (bf16 ws). rot=32, half=16.
__global__ __launch_bounds__(256)
void rope_kernel(u16* __restrict__ Q, u16* __restrict__ K)
{
  int idx = blockIdx.x * 256 + threadIdx.x;   // 2 * 16 * 2048 * 16 = 1048576
  int i = idx & 15;
  int s = (idx >> 4) & 2047;
  int head = (idx >> 15) & 15;
  u16* buf = (idx >> 19) ? K : Q;
  long base = ((long)head * 2048 + s) * 128;
  float inv_freq = exp2f(-(float)i * 0.83048202372184058696f); // 10000^(-i/16)
  float ang = (float)s * inv_freq;
  float c = cosf(ang), sn = sinf(ang);
  float x1 = bf2f(buf[base + i]);
  float x2 = bf2f(buf[base + i + 16]);
  buf[base + i]      = f2bf(x1 * c - x2 * sn);
  buf[base + i + 16] = f2bf(x2 * c + x1 * sn);
}

// causal softmax over row [0..row], zeros above the diagonal; in-place bf16
__global__ __launch_bounds__(256)
void softmax_kernel(u16* __restrict__ SP)
{
  int row = blockIdx.x;
  int z = blockIdx.y;
  u16* p = SP + ((long)z * 2048 + row) * 2048;
  int n = row + 1;
  int tid = threadIdx.x;
  __shared__ float red[256];

  float vals[8];
  float m = -1e30f;
  #pragma unroll
  for (int j = 0; j < 8; j++) {
    int t = tid + j * 256;
    vals[j] = (t < n) ? bf2f(p[t]) : -1e30f;
    m = fmaxf(m, vals[j]);
  }
  red[tid] = m; __syncthreads();
  for (int s = 128; s > 0; s >>= 1) {
    if (tid < s) red[tid] = fmaxf(red[tid], red[tid + s]);
    __syncthreads();
  }
  m = red[0];
  __syncthreads();

  float sum = 0.f;
  #pragma unroll
  for (int j = 0; j < 8; j++) {
    int t = tid + j * 256;
    float e = (t < n) ? __expf(vals[j] - m) : 0.f;
    vals[j] = e;
    sum += e;
  }
  red[tid] = sum; __syncthreads();
  for (int s = 128; s > 0; s >>= 1) {
    if (tid < s) red[tid] += red[tid + s];
    __syncthreads();
  }
  float inv = 1.f / red[0];
  #pragma unroll
  for (int j = 0; j < 8; j++) {
    int t = tid + j * 256;
    p[t] = f2bf(vals[j] * inv);   // masked lanes write 0
  }
}

extern "C" void kernel_launch(void* const* d_in, const int* in_sizes, int n_in,
                              void* d_out, int out_size, void* d_ws, size_t ws_size,
                              hipStream_t stream)
{
  const float* hidden = (const float*)d_in[0];   // [2048][2048] f32
  const float* Wqkv   = (const float*)d_in[1];   // [2048][6144] f32
  const float* bqkv   = (const float*)d_in[2];   // [6144] f32
  const float* Wd     = (const float*)d_in[3];   // [2048][2048] f32
  const float* bd     = (const float*)d_in[4];   // [2048] f32
  float* out = (float*)d_out;                    // [2048][2048] f32

  char* ws = (char*)d_ws;
  u16* Q   = (u16*)(ws);                      //  8 MB  [16][2048][128] bf16
  u16* Kb  = (u16*)(ws + (8ull  << 20));      //  8 MB  [16][2048][128]
  u16* Vt  = (u16*)(ws + (16ull << 20));      //  8 MB  [16][128][2048]
  u16* ctx = (u16*)(ws + (24ull << 20));      //  8 MB  [2048][2048]
  char* regA = ws + (32ull << 20);            // overlay region

  const long HS = 2048L * 128;   // per-head stride for Q/K/Vt (elements)
  const bool fast = ws_size >= (64ull << 20);

  if (fast) {
    u16* hidden_bf = (u16*)(regA);                  // 8 MB (phase 1) / later Wd_t
    u16* Wqkv_t    = (u16*)(regA + (8ull << 20));   // 24 MB (phase 1) / later S
    u16* Wd_t      = (u16*)(regA);                  // 8 MB (phase 4)
    u16* S         = (u16*)(regA + (8ull << 20));   // S region after Wqkv_t dead

    size_t sAvail = ws_size - (40ull << 20);
    int gh = (int)(sAvail / (8ull << 20));
    if (gh > 4) gh = 4;
    if (gh < 1) gh = 1;

    // 1) prep: hidden -> bf16, Wqkv -> bf16 [N][K]
    convert_bf16_kernel<<<dim3(4096), 256, 0, stream>>>(hidden, hidden_bf, 1048576);
    transpose_bf16_kernel<<<dim3(192, 64), 256, 0, stream>>>(Wqkv, Wqkv_t, 2048, 6144);

    // 2) QKV GEMM (all bf16) + scatter
    gemm_kernel<<<dim3(48, 16, 1), 256, 0, stream>>>(
        hidden_bf, Wqkv_t, 2048, 2048, 2048, 0, 0, /*mode*/0, 0, 0, 0, bqkv,
        Q, Kb, Vt, nullptr);

    // 3) RoPE; transpose Wd into regA (hidden_bf now dead)
    rope_kernel<<<dim3(4096), 256, 0, stream>>>(Q, Kb);
    transpose_bf16_kernel<<<dim3(64, 64), 256, 0, stream>>>(Wd, Wd_t, 2048, 2048);

    // 4) attention per head group (S overlays Wqkv_t region)
    for (int h0 = 0; h0 < 16; h0 += gh) {
      int g = 16 - h0 < gh ? 16 - h0 : gh;
      gemm_kernel<<<dim3(16, 16, g), 256, 0, stream>>>(
          Q + h0 * HS, Kb + h0 * HS, 128, 128, 128, HS, HS,
          /*mode*/1, h0, 0, 0, nullptr, S, nullptr, nullptr, nullptr);
      softmax_kernel<<<dim3(2048, g), 256, 0, stream>>>(S);
      gemm_kernel<<<dim3(1, 16, g), 256, 0, stream>>>(
          S, Vt + h0 * HS, 2048, 2048, 2048, 2048L * 2048, HS,
          /*mode*/2, h0, 0, 0, nullptr, ctx, nullptr, nullptr, nullptr);
    }

    // 5) dense GEMM (bf16) + bias -> f32 out
    gemm_kernel<<<dim3(16, 16, 1), 256, 0, stream>>>(
        ctx, Wd_t, 2048, 2048, 2048, 0, 0, /*mode*/3, 0, 0, 0, bd,
        nullptr, nullptr, nullptr, out);
  } else {
    // fallback: round-2 structure (in-GEMM fp32 transpose staging)
    u16* S = (u16*)(regA);
    size_t avail = ws_size > (32ull << 20) ? ws_size - (32ull << 20) : 0;
    int gh = (int)(avail / (8ull << 20));
    if (gh > 16) gh = 16;
    if (gh < 1)  gh = 1;

    gemm_kernel<<<dim3(48, 16, 1), 256, 0, stream>>>(
        hidden, Wqkv, 2048, 2048, 6144, 0, 0, /*mode*/0, 0, 1, 1, bqkv,
        Q, Kb, Vt, nullptr);
    rope_kernel<<<dim3(4096), 256, 0, stream>>>(Q, Kb);
    for (int h0 = 0; h0 < 16; h0 += gh) {
      int g = 16 - h0 < gh ? 16 - h0 : gh;
      gemm_kernel<<<dim3(16, 16, g), 256, 0, stream>>>(
          Q + h0 * HS, Kb + h0 * HS, 128, 128, 128, HS, HS,
          /*mode*/1, h0, 0, 0, nullptr, S, nullptr, nullptr, nullptr);
      softmax_kernel<<<dim3(2048, g), 256, 0, stream>>>(S);
      gemm_kernel<<<dim3(1, 16, g), 256, 0, stream>>>(
          S, Vt + h0 * HS, 2048, 2048, 2048, 2048L * 2048, HS,
          /*mode*/2, h0, 0, 0, nullptr, ctx, nullptr, nullptr, nullptr);
    }
    gemm_kernel<<<dim3(16, 16, 1), 256, 0, stream>>>(
        ctx, Wd, 2048, 2048, 2048, 0, 0, /*mode*/3, 0, 0, 1, bd,
        nullptr, nullptr, nullptr, out);
  }
}

// Round 4
// 556.650 us; speedup vs baseline: 1.7317x; 1.4147x over previous
//
#include <hip/hip_runtime.h>

typedef unsigned short u16;
typedef __attribute__((ext_vector_type(8))) short short8;
typedef __attribute__((ext_vector_type(4))) float floatx4;

#define DEVI static __device__ __forceinline__

DEVI float bf2f(u16 u) {
  union { unsigned u; float f; } x; x.u = ((unsigned)u) << 16; return x.f;
}
DEVI u16 f2bf(float f) {
  union { float f; unsigned u; } x; x.f = f;
  unsigned r = x.u + 0x7fffu + ((x.u >> 16) & 1u);  // RNE
  return (u16)(r >> 16);
}

#define BM 128
#define BN 128
#define BK 32

// Epilogue modes (1/2 retired in favor of flash_kernel; kept for safety):
// 0: QKV: +bias, scatter Q(scaled)/K/Vt as bf16
// 3: out(f32) = ctx@Wd + bias
__global__ __launch_bounds__(256)
void gemm_kernel(const void* __restrict__ Av, const void* __restrict__ Bv,
                 int K, int lda, int ldb,
                 long sAz, long sBz, int mode, int head0, int aF32, int bF32,
                 const float* __restrict__ bias,
                 u16* __restrict__ out0, u16* __restrict__ out1,
                 u16* __restrict__ out2, float* __restrict__ outf)
{
  const int bn = blockIdx.x, bm = blockIdx.y, z = blockIdx.z;
  const int m0 = bm * BM, n0 = bn * BN;
  if (mode == 1 && n0 > m0 + (BM - 1)) return;
  int kEnd = K;
  if (mode == 2) { int ke = m0 + BM; kEnd = ke < K ? ke : K; }

  const float* Af = (const float*)Av;
  const u16*   Ab = (const u16*)Av + (long)z * sAz;
  const float* Bf = (const float*)Bv;
  const u16*   Bb = (const u16*)Bv + (long)z * sBz;

  __shared__ __align__(16) u16 As[BM * BK];   // [m][k] bf16
  __shared__ __align__(16) u16 Bs[BN * BK];   // [n][k] bf16

  const int tid  = threadIdx.x;
  const int lane = tid & 63;
  const int wave = tid >> 6;
  const int wm   = (wave & 1) * 64;
  const int wn   = (wave >> 1) * 64;
  const int lr   = lane & 15;
  const int quad = lane >> 4;

  floatx4 acc[4][4];
  #pragma unroll
  for (int i = 0; i < 4; i++)
    #pragma unroll
    for (int j = 0; j < 4; j++)
      acc[i][j] = floatx4{0.f, 0.f, 0.f, 0.f};

  for (int k0 = 0; k0 < kEnd; k0 += BK) {
    __syncthreads();
    if (aF32) {
      #pragma unroll
      for (int L = tid; L < 1024; L += 256) {
        int row = L >> 3, c4 = (L & 7) * 4;
        float4 v = *(const float4*)(Af + (long)(m0 + row) * lda + k0 + c4);
        ushort4 p;
        p.x = f2bf(v.x); p.y = f2bf(v.y); p.z = f2bf(v.z); p.w = f2bf(v.w);
        *(ushort4*)(&As[row * BK + c4]) = p;
      }
    } else {
      #pragma unroll
      for (int L = tid; L < 512; L += 256) {
        int row = L >> 2, c8 = (L & 3) * 8;
        uint4 v = *(const uint4*)(Ab + (long)(m0 + row) * lda + k0 + c8);
        *(uint4*)(&As[row * BK + c8]) = v;
      }
    }
    if (bF32) {
      #pragma unroll
      for (int L = tid; L < 1024; L += 256) {
        int kr = L >> 5, n4 = (L & 31) * 4;
        float4 v = *(const float4*)(Bf + (long)(k0 + kr) * ldb + n0 + n4);
        Bs[(n4 + 0) * BK + kr] = f2bf(v.x);
        Bs[(n4 + 1) * BK + kr] = f2bf(v.y);
        Bs[(n4 + 2) * BK + kr] = f2bf(v.z);
        Bs[(n4 + 3) * BK + kr] = f2bf(v.w);
      }
    } else {
      #pragma unroll
      for (int L = tid; L < 512; L += 256) {
        int row = L >> 2, c8 = (L & 3) * 8;
        uint4 v = *(const uint4*)(Bb + (long)(n0 + row) * ldb + k0 + c8);
        *(uint4*)(&Bs[row * BK + c8]) = v;
      }
    }
    __syncthreads();

    short8 af[4], bf[4];
    #pragma unroll
    for (int i = 0; i < 4; i++)
      af[i] = *(const short8*)(&As[(wm + i * 16 + lr) * BK + quad * 8]);
    #pragma unroll
    for (int j = 0; j < 4; j++)
      bf[j] = *(const short8*)(&Bs[(wn + j * 16 + lr) * BK + quad * 8]);
    #pragma unroll
    for (int i = 0; i < 4; i++)
      #pragma unroll
      for (int j = 0; j < 4; j++)
        acc[i][j] = __builtin_amdgcn_mfma_f32_16x16x32_bf16(af[i], bf[j], acc[i][j], 0, 0, 0);
  }

  #pragma unroll
  for (int i = 0; i < 4; i++) {
    #pragma unroll
    for (int j = 0; j < 4; j++) {
      #pragma unroll
      for (int r = 0; r < 4; r++) {
        int row = m0 + wm + i * 16 + quad * 4 + r;
        int col = n0 + wn + j * 16 + lr;
        float v = acc[i][j][r];
        if (mode == 0) {
          v += bias[col];
          int head = col / 384;
          int w = col - head * 384;
          long hbase = (long)head * 2048 * 128;
          if (w < 128) {        // Q, pre-scaled by 1/sqrt(128)
            out0[hbase + (long)row * 128 + w] = f2bf(v * 0.08838834764831845f);
          } else if (w < 256) { // K
            out1[hbase + (long)row * 128 + (w - 128)] = f2bf(v);
          } else {              // V -> Vt[head][d][t]
            out2[hbase + (long)(w - 256) * 2048 + row] = f2bf(v);
          }
        } else if (mode == 1) {
          out0[((long)z * 2048 + row) * 2048 + col] = f2bf(v);
        } else if (mode == 2) {
          out0[(long)row * 2048 + (head0 + z) * 128 + col] = f2bf(v);
        } else {
          outf[(long)row * 2048 + col] = v + bias[col];
        }
      }
    }
  }
}

// ---------------- fused flash attention ----------------
// grid (16 pair-slots, 16 heads), 256 threads. Each WG handles Q-blocks
// p and 31-p (64 rows each): exactly 17 K-tile iterations per WG (balanced).
// LDS slab layout ("[x][32]" BK-chunks, the verified m93 bank pattern).
__global__ __launch_bounds__(256)
void flash_kernel(const u16* __restrict__ Qg, const u16* __restrict__ Kg,
                  const u16* __restrict__ Vg, u16* __restrict__ ctx)
{
  const int pr = blockIdx.x, head = blockIdx.y;
  const long HS = 2048L * 128;
  const u16* Qh = Qg + (long)head * HS;
  const u16* Kh = Kg + (long)head * HS;
  const u16* Vh = Vg + (long)head * HS;

  __shared__ __align__(16) u16 q_s[4 * 64 * 32];    // 16 KB  Q [m][d]
  __shared__ __align__(16) u16 kv_s[4 * 128 * 32];  // 32 KB  K [t][d], then V [d][t]
  __shared__ __align__(16) u16 p_s[4 * 64 * 40];    // 20 KB  P [m][t], padded stride 40
  __shared__ float m_sh[64], l_sh[64], al_sh[64];
  __shared__ float pm[4][64], ps[4][64];

  const int tid  = threadIdx.x;
  const int lane = tid & 63, wv = tid >> 6;
  const int lr   = lane & 15, quad = lane >> 4;
  const int wn   = wv * 32;

  for (int qq = 0; qq < 2; qq++) {
    const int qb  = qq ? (31 - pr) : pr;
    const int nkt = (qb >> 1) + 1;

    __syncthreads();
    // stage Q tile (64 x 128)
    #pragma unroll
    for (int L = tid; L < 1024; L += 256) {
      int row = L >> 4, c8 = (L & 15) * 8;
      uint4 x = *(const uint4*)(Qh + (long)(qb * 64 + row) * 128 + c8);
      *(uint4*)(&q_s[(c8 >> 5) * 2048 + row * 32 + (c8 & 31)]) = x;
    }
    if (tid < 64) { m_sh[tid] = -1e30f; l_sh[tid] = 0.f; }

    floatx4 o[4][2];
    #pragma unroll
    for (int i = 0; i < 4; i++)
      #pragma unroll
      for (int j = 0; j < 2; j++)
        o[i][j] = floatx4{0.f, 0.f, 0.f, 0.f};

    for (int kb = 0; kb < nkt; kb++) {
      __syncthreads();                       // prev PV done with kv_s/p_s
      // stage K (128 x 128) -> LDS; prefetch V tile -> regs
      uint4 vr[8];
      #pragma unroll
      for (int L = tid, it = 0; it < 8; L += 256, it++) {
        int row = L >> 4, c8 = (L & 15) * 8;
        uint4 x = *(const uint4*)(Kh + (long)(kb * 128 + row) * 128 + c8);
        *(uint4*)(&kv_s[(c8 >> 5) * 4096 + row * 32 + (c8 & 31)]) = x;
        vr[it] = *(const uint4*)(Vh + (long)row * 2048 + kb * 128 + c8);
      }
      __syncthreads();                       // K (and Q) ready

      // S = Q K^T : acc[4 row-tiles][2 col-tiles]
      floatx4 sa[4][2];
      #pragma unroll
      for (int i = 0; i < 4; i++)
        #pragma unroll
        for (int j = 0; j < 2; j++)
          sa[i][j] = floatx4{0.f, 0.f, 0.f, 0.f};
      #pragma unroll
      for (int kt = 0; kt < 4; kt++) {
        short8 af[4], bf[2];
        #pragma unroll
        for (int i = 0; i < 4; i++)
          af[i] = *(const short8*)(&q_s[kt * 2048 + (i * 16 + lr) * 32 + quad * 8]);
        #pragma unroll
        for (int j = 0; j < 2; j++)
          bf[j] = *(const short8*)(&kv_s[kt * 4096 + (wn + j * 16 + lr) * 32 + quad * 8]);
        #pragma unroll
        for (int i = 0; i < 4; i++)
          #pragma unroll
          for (int j = 0; j < 2; j++)
            sa[i][j] = __builtin_amdgcn_mfma_f32_16x16x32_bf16(af[i], bf[j], sa[i][j], 0, 0, 0);
      }

      if (kb == nkt - 1) {                   // causal mask, last tile only
        #pragma unroll
        for (int i = 0; i < 4; i++)
          #pragma unroll
          for (int j = 0; j < 2; j++)
            #pragma unroll
            for (int r = 0; r < 4; r++) {
              int cg = kb * 128 + wn + j * 16 + lr;
              int rg = qb * 64 + i * 16 + quad * 4 + r;
              if (cg > rg) sa[i][j][r] = -1e30f;
            }
      }

      // row-max partials (reduce over this wave's 32-col strip)
      #pragma unroll
      for (int i = 0; i < 4; i++)
        #pragma unroll
        for (int r = 0; r < 4; r++) {
          float v = fmaxf(sa[i][0][r], sa[i][1][r]);
          v = fmaxf(v, __shfl_xor(v, 1, 16));
          v = fmaxf(v, __shfl_xor(v, 2, 16));
          v = fmaxf(v, __shfl_xor(v, 4, 16));
          v = fmaxf(v, __shfl_xor(v, 8, 16));
          if (lr == i * 4 + r) pm[wv][i * 16 + quad * 4 + r] = v;
        }
      __syncthreads();                       // pm ready; K phase done

      // V regs -> LDS (kv_s now dead as K); concurrently update m/alpha
      #pragma unroll
      for (int L = tid, it = 0; it < 8; L += 256, it++) {
        int row = L >> 4, c8 = (L & 15) * 8;
        *(uint4*)(&kv_s[(c8 >> 5) * 4096 + row * 32 + (c8 & 31)]) = vr[it];
      }
      if (tid < 64) {
        float mx = fmaxf(fmaxf(pm[0][tid], pm[1][tid]), fmaxf(pm[2][tid], pm[3][tid]));
        float nm = fmaxf(m_sh[tid], mx);
        al_sh[tid] = __expf(m_sh[tid] - nm);
        m_sh[tid] = nm;
      }
      __syncthreads();                       // alpha + V ready

      // P = exp(S - m) -> p_s (bf16); row-sum partials
      #pragma unroll
      for (int i = 0; i < 4; i++)
        #pragma unroll
        for (int r = 0; r < 4; r++) {
          int rl = i * 16 + quad * 4 + r;
          float nm = m_sh[rl];
          float e0 = __expf(sa[i][0][r] - nm);
          float e1 = __expf(sa[i][1][r] - nm);
          p_s[wv * 2560 + rl * 40 + lr]      = f2bf(e0);
          p_s[wv * 2560 + rl * 40 + 16 + lr] = f2bf(e1);
          float sm = e0 + e1;
          sm += __shfl_xor(sm, 1, 16);
          sm += __shfl_xor(sm, 2, 16);
          sm += __shfl_xor(sm, 4, 16);
          sm += __shfl_xor(sm, 8, 16);
          if (lr == i * 4 + r) ps[wv][rl] = sm;
        }
      __syncthreads();                       // p_s, ps ready

      if (tid < 64)
        l_sh[tid] = l_sh[tid] * al_sh[tid]
                  + ps[0][tid] + ps[1][tid] + ps[2][tid] + ps[3][tid];

      // O rescale + PV MFMA (P [m][t] x V [d][t])
      #pragma unroll
      for (int i = 0; i < 4; i++)
        #pragma unroll
        for (int r = 0; r < 4; r++) {
          float a = al_sh[i * 16 + quad * 4 + r];
          o[i][0][r] *= a;
          o[i][1][r] *= a;
        }
      #pragma unroll
      for (int kt = 0; kt < 4; kt++) {
        short8 pa[4], vb[2];
        #pragma unroll
        for (int i = 0; i < 4; i++)
          pa[i] = *(const short8*)(&p_s[kt * 2560 + (i * 16 + lr) * 40 + quad * 8]);
        #pragma unroll
        for (int j = 0; j < 2; j++)
          vb[j] = *(const short8*)(&kv_s[kt * 4096 + (wn + j * 16 + lr) * 32 + quad * 8]);
        #pragma unroll
        for (int i = 0; i < 4; i++)
          #pragma unroll
          for (int j = 0; j < 2; j++)
            o[i][j] = __builtin_amdgcn_mfma_f32_16x16x32_bf16(pa[i], vb[j], o[i][j], 0, 0, 0);
      }
    } // kb

    __syncthreads();                         // l_sh final
    #pragma unroll
    for (int i = 0; i < 4; i++)
      #pragma unroll
      for (int r = 0; r < 4; r++) {
        int rl = i * 16 + quad * 4 + r;
        float inv = 1.f / l_sh[rl];
        #pragma unroll
        for (int j = 0; j < 2; j++)
          ctx[(long)(qb * 64 + rl) * 2048 + head * 128 + wn + j * 16 + lr] =
              f2bf(o[i][j][r] * inv);
      }
  } // qq
}

// fp32 -> bf16 same-layout convert, float4/thread
__global__ __launch_bounds__(256)
void convert_bf16_kernel(const float* __restrict__ in, u16* __restrict__ out, long n4)
{
  long i = (long)blockIdx.x * 256 + threadIdx.x;
  if (i < n4) {
    float4 v = ((const float4*)in)[i];
    ushort4 p;
    p.x = f2bf(v.x); p.y = f2bf(v.y); p.z = f2bf(v.z); p.w = f2bf(v.w);
    ((ushort4*)out)[i] = p;
  }
}

// fp32 [K][N] -> bf16 [N][K] transpose+convert. 32x32 tiles.
__global__ __launch_bounds__(256)
void transpose_bf16_kernel(const float* __restrict__ in, u16* __restrict__ out,
                           int K, int N)
{
  __shared__ float t[32][33];
  int n0 = blockIdx.x * 32, k0 = blockIdx.y * 32;
  int tx = threadIdx.x & 31, ty = threadIdx.x >> 5;
  #pragma unroll
  for (int i = 0; i < 4; i++)
    t[ty + i * 8][tx] = in[(long)(k0 + ty + i * 8) * N + n0 + tx];
  __syncthreads();
  #pragma unroll
  for (int i = 0; i < 4; i++)
    out[(long)(n0 + ty + i * 8) * K + k0 + tx] = f2bf(t[tx][ty + i * 8]);
}

// RoPE in-place on first 32 dims of Q and K (bf16 ws). rot=32, half=16.
__global__ __launch_bounds__(256)
void rope_kernel(u16* __restrict__ Q, u16* __restrict__ K)
{
  int idx = blockIdx.x * 256 + threadIdx.x;
  int i = idx & 15;
  int s = (idx >> 4) & 2047;
  int head = (idx >> 15) & 15;
  u16* buf = (idx >> 19) ? K : Q;
  long base = ((long)head * 2048 + s) * 128;
  float inv_freq = exp2f(-(float)i * 0.83048202372184058696f); // 10000^(-i/16)
  float ang = (float)s * inv_freq;
  float c = cosf(ang), sn = sinf(ang);
  float x1 = bf2f(buf[base + i]);
  float x2 = bf2f(buf[base + i + 16]);
  buf[base + i]      = f2bf(x1 * c - x2 * sn);
  buf[base + i + 16] = f2bf(x2 * c + x1 * sn);
}

extern "C" void kernel_launch(void* const* d_in, const int* in_sizes, int n_in,
                              void* d_out, int out_size, void* d_ws, size_t ws_size,
                              hipStream_t stream)
{
  const float* hidden = (const float*)d_in[0];   // [2048][2048] f32
  const float* Wqkv   = (const float*)d_in[1];   // [2048][6144] f32
  const float* bqkv   = (const float*)d_in[2];   // [6144] f32
  const float* Wd     = (const float*)d_in[3];   // [2048][2048] f32
  const float* bd     = (const float*)d_in[4];   // [2048] f32
  float* out = (float*)d_out;                    // [2048][2048] f32

  char* ws = (char*)d_ws;
  u16* Q   = (u16*)(ws);                      //  8 MB  [16][2048][128] bf16
  u16* Kb  = (u16*)(ws + (8ull  << 20));      //  8 MB  [16][2048][128]
  u16* Vt  = (u16*)(ws + (16ull << 20));      //  8 MB  [16][128][2048]
  u16* ctx = (u16*)(ws + (24ull << 20));      //  8 MB  [2048][2048]
  char* regA = ws + (32ull << 20);            // overlay region

  const bool fast = ws_size >= (64ull << 20);

  if (fast) {
    u16* hidden_bf = (u16*)(regA);                  // 8 MB, then Wd_t
    u16* Wqkv_t    = (u16*)(regA + (8ull << 20));   // 24 MB
    u16* Wd_t      = (u16*)(regA);

    convert_bf16_kernel<<<dim3(4096), 256, 0, stream>>>(hidden, hidden_bf, 1048576);
    transpose_bf16_kernel<<<dim3(192, 64), 256, 0, stream>>>(Wqkv, Wqkv_t, 2048, 6144);

    gemm_kernel<<<dim3(48, 16, 1), 256, 0, stream>>>(
        hidden_bf, Wqkv_t, 2048, 2048, 2048, 0, 0, /*mode*/0, 0, 0, 0, bqkv,
        Q, Kb, Vt, nullptr);

    rope_kernel<<<dim3(4096), 256, 0, stream>>>(Q, Kb);
    transpose_bf16_kernel<<<dim3(64, 64), 256, 0, stream>>>(Wd, Wd_t, 2048, 2048);

    flash_kernel<<<dim3(16, 16), 256, 0, stream>>>(Q, Kb, Vt, ctx);

    gemm_kernel<<<dim3(16, 16, 1), 256, 0, stream>>>(
        ctx, Wd_t, 2048, 2048, 2048, 0, 0, /*mode*/3, 0, 0, 0, bd,
        nullptr, nullptr, nullptr, out);
  } else {
    gemm_kernel<<<dim3(48, 16, 1), 256, 0, stream>>>(
        hidden, Wqkv, 2048, 2048, 6144, 0, 0, /*mode*/0, 0, 1, 1, bqkv,
        Q, Kb, Vt, nullptr);
    rope_kernel<<<dim3(4096), 256, 0, stream>>>(Q, Kb);
    flash_kernel<<<dim3(16, 16), 256, 0, stream>>>(Q, Kb, Vt, ctx);
    gemm_kernel<<<dim3(16, 16, 1), 256, 0, stream>>>(
        ctx, Wd, 2048, 2048, 2048, 0, 0, /*mode*/3, 0, 0, 1, bd,
        nullptr, nullptr, nullptr, out);
  }
}

// Round 5
// 474.671 us; speedup vs baseline: 2.0308x; 1.1727x over previous
//
#include <hip/hip_runtime.h>

typedef unsigned short u16;
typedef __attribute__((ext_vector_type(8))) short short8;
typedef __attribute__((ext_vector_type(4))) float floatx4;

#define DEVI static __device__ __forceinline__

DEVI float bf2f(u16 u) {
  union { unsigned u; float f; } x; x.u = ((unsigned)u) << 16; return x.f;
}
DEVI u16 f2bf(float f) {
  union { float f; unsigned u; } x; x.f = f;
  unsigned r = x.u + 0x7fffu + ((x.u >> 16) & 1u);  // RNE
  return (u16)(r >> 16);
}

#define BM 128
#define BN 128
#define BK 32

// Epilogue modes:
// 0: QKV: +bias, scatter Q(scaled)/K/Vt as bf16
// 3: out(f32) = ctx@Wd + bias
__global__ __launch_bounds__(256)
void gemm_kernel(const void* __restrict__ Av, const void* __restrict__ Bv,
                 int K, int lda, int ldb,
                 long sAz, long sBz, int mode, int head0, int aF32, int bF32,
                 const float* __restrict__ bias,
                 u16* __restrict__ out0, u16* __restrict__ out1,
                 u16* __restrict__ out2, float* __restrict__ outf)
{
  const int bn = blockIdx.x, bm = blockIdx.y, z = blockIdx.z;
  const int m0 = bm * BM, n0 = bn * BN;
  if (mode == 1 && n0 > m0 + (BM - 1)) return;
  int kEnd = K;
  if (mode == 2) { int ke = m0 + BM; kEnd = ke < K ? ke : K; }

  const float* Af = (const float*)Av;
  const u16*   Ab = (const u16*)Av + (long)z * sAz;
  const float* Bf = (const float*)Bv;
  const u16*   Bb = (const u16*)Bv + (long)z * sBz;

  __shared__ __align__(16) u16 As[BM * BK];   // [m][k] bf16
  __shared__ __align__(16) u16 Bs[BN * BK];   // [n][k] bf16

  const int tid  = threadIdx.x;
  const int lane = tid & 63;
  const int wave = tid >> 6;
  const int wm   = (wave & 1) * 64;
  const int wn   = (wave >> 1) * 64;
  const int lr   = lane & 15;
  const int quad = lane >> 4;

  floatx4 acc[4][4];
  #pragma unroll
  for (int i = 0; i < 4; i++)
    #pragma unroll
    for (int j = 0; j < 4; j++)
      acc[i][j] = floatx4{0.f, 0.f, 0.f, 0.f};

  for (int k0 = 0; k0 < kEnd; k0 += BK) {
    __syncthreads();
    if (aF32) {
      #pragma unroll
      for (int L = tid; L < 1024; L += 256) {
        int row = L >> 3, c4 = (L & 7) * 4;
        float4 v = *(const float4*)(Af + (long)(m0 + row) * lda + k0 + c4);
        ushort4 p;
        p.x = f2bf(v.x); p.y = f2bf(v.y); p.z = f2bf(v.z); p.w = f2bf(v.w);
        *(ushort4*)(&As[row * BK + c4]) = p;
      }
    } else {
      #pragma unroll
      for (int L = tid; L < 512; L += 256) {
        int row = L >> 2, c8 = (L & 3) * 8;
        uint4 v = *(const uint4*)(Ab + (long)(m0 + row) * lda + k0 + c8);
        *(uint4*)(&As[row * BK + c8]) = v;
      }
    }
    if (bF32) {
      #pragma unroll
      for (int L = tid; L < 1024; L += 256) {
        int kr = L >> 5, n4 = (L & 31) * 4;
        float4 v = *(const float4*)(Bf + (long)(k0 + kr) * ldb + n0 + n4);
        Bs[(n4 + 0) * BK + kr] = f2bf(v.x);
        Bs[(n4 + 1) * BK + kr] = f2bf(v.y);
        Bs[(n4 + 2) * BK + kr] = f2bf(v.z);
        Bs[(n4 + 3) * BK + kr] = f2bf(v.w);
      }
    } else {
      #pragma unroll
      for (int L = tid; L < 512; L += 256) {
        int row = L >> 2, c8 = (L & 3) * 8;
        uint4 v = *(const uint4*)(Bb + (long)(n0 + row) * ldb + k0 + c8);
        *(uint4*)(&Bs[row * BK + c8]) = v;
      }
    }
    __syncthreads();

    short8 af[4], bf[4];
    #pragma unroll
    for (int i = 0; i < 4; i++)
      af[i] = *(const short8*)(&As[(wm + i * 16 + lr) * BK + quad * 8]);
    #pragma unroll
    for (int j = 0; j < 4; j++)
      bf[j] = *(const short8*)(&Bs[(wn + j * 16 + lr) * BK + quad * 8]);
    #pragma unroll
    for (int i = 0; i < 4; i++)
      #pragma unroll
      for (int j = 0; j < 4; j++)
        acc[i][j] = __builtin_amdgcn_mfma_f32_16x16x32_bf16(af[i], bf[j], acc[i][j], 0, 0, 0);
  }

  #pragma unroll
  for (int i = 0; i < 4; i++) {
    #pragma unroll
    for (int j = 0; j < 4; j++) {
      #pragma unroll
      for (int r = 0; r < 4; r++) {
        int row = m0 + wm + i * 16 + quad * 4 + r;
        int col = n0 + wn + j * 16 + lr;
        float v = acc[i][j][r];
        if (mode == 0) {
          v += bias[col];
          int head = col / 384;
          int w = col - head * 384;
          long hbase = (long)head * 2048 * 128;
          if (w < 128) {        // Q, pre-scaled by 1/sqrt(128)
            out0[hbase + (long)row * 128 + w] = f2bf(v * 0.08838834764831845f);
          } else if (w < 256) { // K
            out1[hbase + (long)row * 128 + (w - 128)] = f2bf(v);
          } else {              // V -> Vt[head][d][t]
            out2[hbase + (long)(w - 256) * 2048 + row] = f2bf(v);
          }
        } else if (mode == 1) {
          out0[((long)z * 2048 + row) * 2048 + col] = f2bf(v);
        } else if (mode == 2) {
          out0[(long)row * 2048 + (head0 + z) * 128 + col] = f2bf(v);
        } else {
          outf[(long)row * 2048 + col] = v + bias[col];
        }
      }
    }
  }
}

// ---------------- fused flash attention, v2 ----------------
// grid (32 slots, 16 heads) = 512 WGs; qb = head<8 ? slot : 31-slot so the
// two co-resident WGs per CU (L, L+256) have complementary tile counts
// (sum = 17). Q in registers; K and V staged to separate LDS buffers (no
// register prefetch -> no spill); P overlays the dead K region.
// LDS = 32 + 32 + ~3 KB -> 2 blocks/CU.
__global__ __launch_bounds__(256, 2)
void flash_kernel(const u16* __restrict__ Qg, const u16* __restrict__ Kg,
                  const u16* __restrict__ Vg, u16* __restrict__ ctx)
{
  const int slot = blockIdx.x, head = blockIdx.y;
  const int qb   = (head < 8) ? slot : 31 - slot;
  const int nkt  = (qb >> 1) + 1;
  const long HS  = 2048L * 128;
  const u16* Qh = Qg + (long)head * HS;
  const u16* Kh = Kg + (long)head * HS;
  const u16* Vh = Vg + (long)head * HS;

  __shared__ __align__(16) u16 kv_s[4 * 128 * 32]; // 32 KB: K slabs; P overlays
  __shared__ __align__(16) u16 v_s [4 * 128 * 32]; // 32 KB: V slabs [d][t]
  __shared__ float m_sh[64], l_sh[64], al_sh[64];
  __shared__ float pm[4][64], ps[4][64];

  const int tid  = threadIdx.x;
  const int lane = tid & 63, wv = tid >> 6;
  const int lr   = lane & 15, quad = lane >> 4;
  const int wn   = wv * 32;

  // Q fragments in registers: qf[kt][i] = Q[qb*64 + i*16+lr][kt*32 + quad*8 ..+7]
  short8 qf[4][4];
  #pragma unroll
  for (int kt = 0; kt < 4; kt++)
    #pragma unroll
    for (int i = 0; i < 4; i++)
      qf[kt][i] = *(const short8*)(Qh + (long)(qb * 64 + i * 16 + lr) * 128
                                   + kt * 32 + quad * 8);

  if (tid < 64) { m_sh[tid] = -1e30f; l_sh[tid] = 0.f; }

  floatx4 o[4][2];
  #pragma unroll
  for (int i = 0; i < 4; i++)
    #pragma unroll
    for (int j = 0; j < 2; j++)
      o[i][j] = floatx4{0.f, 0.f, 0.f, 0.f};

  for (int kb = 0; kb < nkt; kb++) {
    __syncthreads();                        // b_A: kv_s/v_s free (prev PV done)
    // stage K and V tiles (each 128x128 bf16), slab-major chunk mapping:
    // chunk C -> slab s=C>>9, row=(C>>2)&127, ch=C&3  (16B per chunk)
    #pragma unroll
    for (int it = 0; it < 8; it++) {
      int C = it * 256 + tid;
      int s = C >> 9, row = (C >> 2) & 127, ch = C & 3;
      int col = s * 32 + ch * 8;
      uint4 kx = *(const uint4*)(Kh + (long)(kb * 128 + row) * 128 + col);
      uint4 vx = *(const uint4*)(Vh + (long)row * 2048 + kb * 128 + col);
      *(uint4*)(&kv_s[s * 4096 + row * 32 + ch * 8]) = kx;
      *(uint4*)(&v_s [s * 4096 + row * 32 + ch * 8]) = vx;
    }
    __syncthreads();                        // b_B: staging visible

    // S = Q K^T
    floatx4 sa[4][2];
    #pragma unroll
    for (int i = 0; i < 4; i++)
      #pragma unroll
      for (int j = 0; j < 2; j++)
        sa[i][j] = floatx4{0.f, 0.f, 0.f, 0.f};
    #pragma unroll
    for (int kt = 0; kt < 4; kt++) {
      short8 bf[2];
      #pragma unroll
      for (int j = 0; j < 2; j++)
        bf[j] = *(const short8*)(&kv_s[kt * 4096 + (wn + j * 16 + lr) * 32 + quad * 8]);
      #pragma unroll
      for (int i = 0; i < 4; i++)
        #pragma unroll
        for (int j = 0; j < 2; j++)
          sa[i][j] = __builtin_amdgcn_mfma_f32_16x16x32_bf16(qf[kt][i], bf[j], sa[i][j], 0, 0, 0);
    }

    if (kb == nkt - 1) {                    // causal mask, last tile only
      #pragma unroll
      for (int i = 0; i < 4; i++)
        #pragma unroll
        for (int j = 0; j < 2; j++)
          #pragma unroll
          for (int r = 0; r < 4; r++) {
            int cg = kb * 128 + wn + j * 16 + lr;
            int rg = qb * 64 + i * 16 + quad * 4 + r;
            if (cg > rg) sa[i][j][r] = -1e30f;
          }
    }

    // row-max partials over this wave's 32-col strip
    #pragma unroll
    for (int i = 0; i < 4; i++)
      #pragma unroll
      for (int r = 0; r < 4; r++) {
        float v = fmaxf(sa[i][0][r], sa[i][1][r]);
        v = fmaxf(v, __shfl_xor(v, 1, 16));
        v = fmaxf(v, __shfl_xor(v, 2, 16));
        v = fmaxf(v, __shfl_xor(v, 4, 16));
        v = fmaxf(v, __shfl_xor(v, 8, 16));
        if (lr == i * 4 + r) pm[wv][i * 16 + quad * 4 + r] = v;
      }
    __syncthreads();                        // b_C: pm ready; K reads done

    if (tid < 64) {
      float mx = fmaxf(fmaxf(pm[0][tid], pm[1][tid]), fmaxf(pm[2][tid], pm[3][tid]));
      float nm = fmaxf(m_sh[tid], mx);
      al_sh[tid] = __expf(m_sh[tid] - nm);
      m_sh[tid] = nm;
    }
    __syncthreads();                        // b_D: m/alpha ready

    // P = exp(S - m) -> overlay into kv_s (stride-40 slab layout); row sums
    #pragma unroll
    for (int i = 0; i < 4; i++)
      #pragma unroll
      for (int r = 0; r < 4; r++) {
        int rl = i * 16 + quad * 4 + r;
        float nm = m_sh[rl];
        float e0 = __expf(sa[i][0][r] - nm);
        float e1 = __expf(sa[i][1][r] - nm);
        kv_s[wv * 2560 + rl * 40 + lr]      = f2bf(e0);
        kv_s[wv * 2560 + rl * 40 + 16 + lr] = f2bf(e1);
        float sm = e0 + e1;
        sm += __shfl_xor(sm, 1, 16);
        sm += __shfl_xor(sm, 2, 16);
        sm += __shfl_xor(sm, 4, 16);
        sm += __shfl_xor(sm, 8, 16);
        if (lr == i * 4 + r) ps[wv][rl] = sm;
      }
    // O rescale (al_sh valid until next b_C)
    #pragma unroll
    for (int i = 0; i < 4; i++)
      #pragma unroll
      for (int r = 0; r < 4; r++) {
        float a = al_sh[i * 16 + quad * 4 + r];
        o[i][0][r] *= a;
        o[i][1][r] *= a;
      }
    __syncthreads();                        // b_E: P + ps ready

    if (tid < 64)
      l_sh[tid] = l_sh[tid] * al_sh[tid]
                + ps[0][tid] + ps[1][tid] + ps[2][tid] + ps[3][tid];

    // PV: O += P (kv_s overlay) x V (v_s)
    #pragma unroll
    for (int kt = 0; kt < 4; kt++) {
      short8 pa[4], vb[2];
      #pragma unroll
      for (int i = 0; i < 4; i++)
        pa[i] = *(const short8*)(&kv_s[kt * 2560 + (i * 16 + lr) * 40 + quad * 8]);
      #pragma unroll
      for (int j = 0; j < 2; j++)
        vb[j] = *(const short8*)(&v_s[kt * 4096 + (wn + j * 16 + lr) * 32 + quad * 8]);
      #pragma unroll
      for (int i = 0; i < 4; i++)
        #pragma unroll
        for (int j = 0; j < 2; j++)
          o[i][j] = __builtin_amdgcn_mfma_f32_16x16x32_bf16(pa[i], vb[j], o[i][j], 0, 0, 0);
    }
  } // kb

  __syncthreads();                          // l_sh final
  #pragma unroll
  for (int i = 0; i < 4; i++)
    #pragma unroll
    for (int r = 0; r < 4; r++) {
      int rl = i * 16 + quad * 4 + r;
      float inv = 1.f / l_sh[rl];
      #pragma unroll
      for (int j = 0; j < 2; j++)
        ctx[(long)(qb * 64 + rl) * 2048 + head * 128 + wn + j * 16 + lr] =
            f2bf(o[i][j][r] * inv);
    }
}

// fp32 -> bf16 same-layout convert, float4/thread
__global__ __launch_bounds__(256)
void convert_bf16_kernel(const float* __restrict__ in, u16* __restrict__ out, long n4)
{
  long i = (long)blockIdx.x * 256 + threadIdx.x;
  if (i < n4) {
    float4 v = ((const float4*)in)[i];
    ushort4 p;
    p.x = f2bf(v.x); p.y = f2bf(v.y); p.z = f2bf(v.z); p.w = f2bf(v.w);
    ((ushort4*)out)[i] = p;
  }
}

// fp32 [K][N] -> bf16 [N][K] transpose+convert. 32x32 tiles.
__global__ __launch_bounds__(256)
void transpose_bf16_kernel(const float* __restrict__ in, u16* __restrict__ out,
                           int K, int N)
{
  __shared__ float t[32][33];
  int n0 = blockIdx.x * 32, k0 = blockIdx.y * 32;
  int tx = threadIdx.x & 31, ty = threadIdx.x >> 5;
  #pragma unroll
  for (int i = 0; i < 4; i++)
    t[ty + i * 8][tx] = in[(long)(k0 + ty + i * 8) * N + n0 + tx];
  __syncthreads();
  #pragma unroll
  for (int i = 0; i < 4; i++)
    out[(long)(n0 + ty + i * 8) * K + k0 + tx] = f2bf(t[tx][ty + i * 8]);
}

// RoPE in-place on first 32 dims of Q and K (bf16 ws). rot=32, half=16.
__global__ __launch_bounds__(256)
void rope_kernel(u16* __restrict__ Q, u16* __restrict__ K)
{
  int idx = blockIdx.x * 256 + threadIdx.x;
  int i = idx & 15;
  int s = (idx >> 4) & 2047;
  int head = (idx >> 15) & 15;
  u16* buf = (idx >> 19) ? K : Q;
  long base = ((long)head * 2048 + s) * 128;
  float inv_freq = exp2f(-(float)i * 0.83048202372184058696f); // 10000^(-i/16)
  float ang = (float)s * inv_freq;
  float c = cosf(ang), sn = sinf(ang);
  float x1 = bf2f(buf[base + i]);
  float x2 = bf2f(buf[base + i + 16]);
  buf[base + i]      = f2bf(x1 * c - x2 * sn);
  buf[base + i + 16] = f2bf(x2 * c + x1 * sn);
}

extern "C" void kernel_launch(void* const* d_in, const int* in_sizes, int n_in,
                              void* d_out, int out_size, void* d_ws, size_t ws_size,
                              hipStream_t stream)
{
  const float* hidden = (const float*)d_in[0];   // [2048][2048] f32
  const float* Wqkv   = (const float*)d_in[1];   // [2048][6144] f32
  const float* bqkv   = (const float*)d_in[2];   // [6144] f32
  const float* Wd     = (const float*)d_in[3];   // [2048][2048] f32
  const float* bd     = (const float*)d_in[4];   // [2048] f32
  float* out = (float*)d_out;                    // [2048][2048] f32

  char* ws = (char*)d_ws;
  u16* Q   = (u16*)(ws);                      //  8 MB  [16][2048][128] bf16
  u16* Kb  = (u16*)(ws + (8ull  << 20));      //  8 MB  [16][2048][128]
  u16* Vt  = (u16*)(ws + (16ull << 20));      //  8 MB  [16][128][2048]
  u16* ctx = (u16*)(ws + (24ull << 20));      //  8 MB  [2048][2048]
  char* regA = ws + (32ull << 20);            // overlay region

  const bool fast = ws_size >= (64ull << 20);

  if (fast) {
    u16* hidden_bf = (u16*)(regA);                  // 8 MB, then Wd_t
    u16* Wqkv_t    = (u16*)(regA + (8ull << 20));   // 24 MB
    u16* Wd_t      = (u16*)(regA);

    convert_bf16_kernel<<<dim3(4096), 256, 0, stream>>>(hidden, hidden_bf, 1048576);
    transpose_bf16_kernel<<<dim3(192, 64), 256, 0, stream>>>(Wqkv, Wqkv_t, 2048, 6144);

    gemm_kernel<<<dim3(48, 16, 1), 256, 0, stream>>>(
        hidden_bf, Wqkv_t, 2048, 2048, 2048, 0, 0, /*mode*/0, 0, 0, 0, bqkv,
        Q, Kb, Vt, nullptr);

    rope_kernel<<<dim3(4096), 256, 0, stream>>>(Q, Kb);
    transpose_bf16_kernel<<<dim3(64, 64), 256, 0, stream>>>(Wd, Wd_t, 2048, 2048);

    flash_kernel<<<dim3(32, 16), 256, 0, stream>>>(Q, Kb, Vt, ctx);

    gemm_kernel<<<dim3(16, 16, 1), 256, 0, stream>>>(
        ctx, Wd_t, 2048, 2048, 2048, 0, 0, /*mode*/3, 0, 0, 0, bd,
        nullptr, nullptr, nullptr, out);
  } else {
    gemm_kernel<<<dim3(48, 16, 1), 256, 0, stream>>>(
        hidden, Wqkv, 2048, 2048, 6144, 0, 0, /*mode*/0, 0, 1, 1, bqkv,
        Q, Kb, Vt, nullptr);
    rope_kernel<<<dim3(4096), 256, 0, stream>>>(Q, Kb);
    flash_kernel<<<dim3(32, 16), 256, 0, stream>>>(Q, Kb, Vt, ctx);
    gemm_kernel<<<dim3(16, 16, 1), 256, 0, stream>>>(
        ctx, Wd, 2048, 2048, 2048, 0, 0, /*mode*/3, 0, 0, 1, bd,
        nullptr, nullptr, nullptr, out);
  }
}

// Round 6
// 402.550 us; speedup vs baseline: 2.3946x; 1.1792x over previous
//
#include <hip/hip_runtime.h>

typedef unsigned short u16;
typedef __attribute__((ext_vector_type(8))) short short8;
typedef __attribute__((ext_vector_type(4))) float floatx4;

#define DEVI static __device__ __forceinline__

DEVI float bf2f(u16 u) {
  union { unsigned u; float f; } x; x.u = ((unsigned)u) << 16; return x.f;
}
DEVI u16 f2bf(float f) {
  union { float f; unsigned u; } x; x.f = f;
  unsigned r = x.u + 0x7fffu + ((x.u >> 16) & 1u);  // RNE
  return (u16)(r >> 16);
}

#define BM 128
#define BN 128
#define BK 32

// Epilogue modes:
// 0: QKV: +bias, scatter Q(scaled)/K/Vt as bf16
// 3: out(f32) = ctx@Wd + bias
__global__ __launch_bounds__(256)
void gemm_kernel(const void* __restrict__ Av, const void* __restrict__ Bv,
                 int K, int lda, int ldb,
                 long sAz, long sBz, int mode, int head0, int aF32, int bF32,
                 const float* __restrict__ bias,
                 u16* __restrict__ out0, u16* __restrict__ out1,
                 u16* __restrict__ out2, float* __restrict__ outf)
{
  const int bn = blockIdx.x, bm = blockIdx.y, z = blockIdx.z;
  const int m0 = bm * BM, n0 = bn * BN;
  if (mode == 1 && n0 > m0 + (BM - 1)) return;
  int kEnd = K;
  if (mode == 2) { int ke = m0 + BM; kEnd = ke < K ? ke : K; }

  const float* Af = (const float*)Av;
  const u16*   Ab = (const u16*)Av + (long)z * sAz;
  const float* Bf = (const float*)Bv;
  const u16*   Bb = (const u16*)Bv + (long)z * sBz;

  __shared__ __align__(16) u16 As[BM * BK];   // [m][k] bf16
  __shared__ __align__(16) u16 Bs[BN * BK];   // [n][k] bf16

  const int tid  = threadIdx.x;
  const int lane = tid & 63;
  const int wave = tid >> 6;
  const int wm   = (wave & 1) * 64;
  const int wn   = (wave >> 1) * 64;
  const int lr   = lane & 15;
  const int quad = lane >> 4;

  floatx4 acc[4][4];
  #pragma unroll
  for (int i = 0; i < 4; i++)
    #pragma unroll
    for (int j = 0; j < 4; j++)
      acc[i][j] = floatx4{0.f, 0.f, 0.f, 0.f};

  for (int k0 = 0; k0 < kEnd; k0 += BK) {
    __syncthreads();
    if (aF32) {
      #pragma unroll
      for (int L = tid; L < 1024; L += 256) {
        int row = L >> 3, c4 = (L & 7) * 4;
        float4 v = *(const float4*)(Af + (long)(m0 + row) * lda + k0 + c4);
        ushort4 p;
        p.x = f2bf(v.x); p.y = f2bf(v.y); p.z = f2bf(v.z); p.w = f2bf(v.w);
        *(ushort4*)(&As[row * BK + c4]) = p;
      }
    } else {
      #pragma unroll
      for (int L = tid; L < 512; L += 256) {
        int row = L >> 2, c8 = (L & 3) * 8;
        uint4 v = *(const uint4*)(Ab + (long)(m0 + row) * lda + k0 + c8);
        *(uint4*)(&As[row * BK + c8]) = v;
      }
    }
    if (bF32) {
      #pragma unroll
      for (int L = tid; L < 1024; L += 256) {
        int kr = L >> 5, n4 = (L & 31) * 4;
        float4 v = *(const float4*)(Bf + (long)(k0 + kr) * ldb + n0 + n4);
        Bs[(n4 + 0) * BK + kr] = f2bf(v.x);
        Bs[(n4 + 1) * BK + kr] = f2bf(v.y);
        Bs[(n4 + 2) * BK + kr] = f2bf(v.z);
        Bs[(n4 + 3) * BK + kr] = f2bf(v.w);
      }
    } else {
      #pragma unroll
      for (int L = tid; L < 512; L += 256) {
        int row = L >> 2, c8 = (L & 3) * 8;
        uint4 v = *(const uint4*)(Bb + (long)(n0 + row) * ldb + k0 + c8);
        *(uint4*)(&Bs[row * BK + c8]) = v;
      }
    }
    __syncthreads();

    short8 af[4], bf[4];
    #pragma unroll
    for (int i = 0; i < 4; i++)
      af[i] = *(const short8*)(&As[(wm + i * 16 + lr) * BK + quad * 8]);
    #pragma unroll
    for (int j = 0; j < 4; j++)
      bf[j] = *(const short8*)(&Bs[(wn + j * 16 + lr) * BK + quad * 8]);
    #pragma unroll
    for (int i = 0; i < 4; i++)
      #pragma unroll
      for (int j = 0; j < 4; j++)
        acc[i][j] = __builtin_amdgcn_mfma_f32_16x16x32_bf16(af[i], bf[j], acc[i][j], 0, 0, 0);
  }

  #pragma unroll
  for (int i = 0; i < 4; i++) {
    #pragma unroll
    for (int j = 0; j < 4; j++) {
      #pragma unroll
      for (int r = 0; r < 4; r++) {
        int row = m0 + wm + i * 16 + quad * 4 + r;
        int col = n0 + wn + j * 16 + lr;
        float v = acc[i][j][r];
        if (mode == 0) {
          v += bias[col];
          int head = col / 384;
          int w = col - head * 384;
          long hbase = (long)head * 2048 * 128;
          if (w < 128) {        // Q, pre-scaled by 1/sqrt(128)
            out0[hbase + (long)row * 128 + w] = f2bf(v * 0.08838834764831845f);
          } else if (w < 256) { // K
            out1[hbase + (long)row * 128 + (w - 128)] = f2bf(v);
          } else {              // V -> Vt[head][d][t]
            out2[hbase + (long)(w - 256) * 2048 + row] = f2bf(v);
          }
        } else if (mode == 1) {
          out0[((long)z * 2048 + row) * 2048 + col] = f2bf(v);
        } else if (mode == 2) {
          out0[(long)row * 2048 + (head0 + z) * 128 + col] = f2bf(v);
        } else {
          outf[(long)row * 2048 + col] = v + bias[col];
        }
      }
    }
  }
}

// ---------------- fused flash attention, v3 ----------------
// grid (32 slots, 16 heads); qb = head<8 ? slot : 31-slot (complementary
// pairing across dispatch halves). WG = 256 thr; wave wv owns Q rows
// [qb*64+wv*16, +16) (row-partition) -> softmax entirely wave-local in
// registers. BN=64 K-tiles; LDS = K 16KB + V 16KB = 32 KB. P (16x68 bf16
// per wave) overlays the dead K buffer. 3 barriers/tile.
__global__ __launch_bounds__(256, 2)
void flash_kernel(const u16* __restrict__ Qg, const u16* __restrict__ Kg,
                  const u16* __restrict__ Vg, u16* __restrict__ ctx)
{
  const int slot = blockIdx.x, head = blockIdx.y;
  const int qb   = (head < 8) ? slot : 31 - slot;
  const int nkt  = qb + 1;               // 64-col K tiles
  const long HS  = 2048L * 128;
  const u16* Qh = Qg + (long)head * HS;
  const u16* Kh = Kg + (long)head * HS;
  const u16* Vh = Vg + (long)head * HS;  // Vt layout [d][t]

  __shared__ __align__(16) u16 k_s[4 * 64 * 32];   // 16 KB  K [kt][n][32]; P overlays
  __shared__ __align__(16) u16 v_s[2 * 128 * 32];  // 16 KB  V [kt2][d][32]

  const int tid  = threadIdx.x;
  const int lane = tid & 63, wv = tid >> 6;
  const int lr   = lane & 15, quad = lane >> 4;
  const int qs   = qb * 64 + wv * 16;    // this wave's strip start row

  // Q fragments: strip row = lr, k = kt*32 + quad*8 .. +7
  short8 qf[4];
  #pragma unroll
  for (int kt = 0; kt < 4; kt++)
    qf[kt] = *(const short8*)(Qh + (long)(qs + lr) * 128 + kt * 32 + quad * 8);

  float m_r[4], l_r[4];
  #pragma unroll
  for (int r = 0; r < 4; r++) { m_r[r] = -1e30f; l_r[r] = 0.f; }

  floatx4 o[8];
  #pragma unroll
  for (int j = 0; j < 8; j++) o[j] = floatx4{0.f, 0.f, 0.f, 0.f};

  const int pbase = wv * 1088;           // P strip: 16 rows x stride 68 u16

  for (int kb = 0; kb < nkt; kb++) {
    __syncthreads();                     // b_A: prev PV reads done
    // stage K (64x128) and V (128x64) tiles; chunk C -> dest u16 C*8.
    // K: C = kt*256 + n*4 + c; C*8 = kt*2048 + n*32 + c*8  (identity)
    // V: C = kt2*512 + d*4 + c; C*8 = kt2*4096 + d*32 + c*8 (identity)
    #pragma unroll
    for (int it = 0; it < 4; it++) {
      int C = it * 256 + tid;
      {
        int kt = C >> 8, n = (C >> 2) & 63, c8 = (C & 3) * 8;
        uint4 x = *(const uint4*)(Kh + (long)(kb * 64 + n) * 128 + kt * 32 + c8);
        *(uint4*)(&k_s[C * 8]) = x;
      }
      {
        int kt2 = C >> 9, d = (C >> 2) & 127, t8 = (C & 3) * 8;
        uint4 x = *(const uint4*)(Vh + (long)d * 2048 + kb * 64 + kt2 * 32 + t8);
        *(uint4*)(&v_s[C * 8]) = x;
      }
    }
    __syncthreads();                     // b_B: staging visible

    // S = Q K^T : strip 16 rows x 64 cols
    floatx4 sa[4];
    #pragma unroll
    for (int j = 0; j < 4; j++) sa[j] = floatx4{0.f, 0.f, 0.f, 0.f};
    #pragma unroll
    for (int kt = 0; kt < 4; kt++) {
      #pragma unroll
      for (int j = 0; j < 4; j++) {
        short8 bf = *(const short8*)(&k_s[kt * 2048 + (j * 16 + lr) * 32 + quad * 8]);
        sa[j] = __builtin_amdgcn_mfma_f32_16x16x32_bf16(qf[kt], bf, sa[j], 0, 0, 0);
      }
    }

    if (kb == nkt - 1) {                 // causal mask (only last tile crosses diag)
      #pragma unroll
      for (int j = 0; j < 4; j++)
        #pragma unroll
        for (int r = 0; r < 4; r++) {
          int cg = kb * 64 + j * 16 + lr;
          int rg = qs + quad * 4 + r;
          if (cg > rg) sa[j][r] = -1e30f;
        }
    }

    // wave-local online softmax: row = quad*4 + r; reduce over lr (width 16)
    float al[4];
    #pragma unroll
    for (int r = 0; r < 4; r++) {
      float v = fmaxf(fmaxf(sa[0][r], sa[1][r]), fmaxf(sa[2][r], sa[3][r]));
      v = fmaxf(v, __shfl_xor(v, 1, 16));
      v = fmaxf(v, __shfl_xor(v, 2, 16));
      v = fmaxf(v, __shfl_xor(v, 4, 16));
      v = fmaxf(v, __shfl_xor(v, 8, 16));
      float nm = fmaxf(m_r[r], v);
      al[r] = __expf(m_r[r] - nm);
      m_r[r] = nm;
    }

    __syncthreads();                     // b_C: all waves done reading K (P overlay next)

    // P = exp(S - m) -> own strip in k_s (stride 68: bank-spread); row sums in regs
    #pragma unroll
    for (int r = 0; r < 4; r++) {
      float s0 = 0.f;
      #pragma unroll
      for (int j = 0; j < 4; j++) {
        float e = __expf(sa[j][r] - m_r[r]);
        k_s[pbase + (quad * 4 + r) * 68 + j * 16 + lr] = f2bf(e);
        s0 += e;
      }
      s0 += __shfl_xor(s0, 1, 16);
      s0 += __shfl_xor(s0, 2, 16);
      s0 += __shfl_xor(s0, 4, 16);
      s0 += __shfl_xor(s0, 8, 16);
      l_r[r] = l_r[r] * al[r] + s0;
    }

    // O rescale (registers)
    #pragma unroll
    for (int j = 0; j < 8; j++)
      #pragma unroll
      for (int r = 0; r < 4; r++)
        o[j][r] *= al[r];

    // PV: O += P(own strip) x V ; same-wave LDS write->read, no barrier needed
    #pragma unroll
    for (int kt2 = 0; kt2 < 2; kt2++) {
      short8 pa = *(const short8*)(&k_s[pbase + lr * 68 + kt2 * 32 + quad * 8]);
      #pragma unroll
      for (int j = 0; j < 8; j++) {
        short8 vb = *(const short8*)(&v_s[kt2 * 4096 + (j * 16 + lr) * 32 + quad * 8]);
        o[j] = __builtin_amdgcn_mfma_f32_16x16x32_bf16(pa, vb, o[j], 0, 0, 0);
      }
    }
  } // kb

  // epilogue: row = qs + quad*4 + r, col d = j*16 + lr
  #pragma unroll
  for (int r = 0; r < 4; r++) {
    float inv = 1.f / l_r[r];
    int row = qs + quad * 4 + r;
    #pragma unroll
    for (int j = 0; j < 8; j++)
      ctx[(long)row * 2048 + head * 128 + j * 16 + lr] = f2bf(o[j][r] * inv);
  }
}

// fp32 -> bf16 same-layout convert, float4/thread
__global__ __launch_bounds__(256)
void convert_bf16_kernel(const float* __restrict__ in, u16* __restrict__ out, long n4)
{
  long i = (long)blockIdx.x * 256 + threadIdx.x;
  if (i < n4) {
    float4 v = ((const float4*)in)[i];
    ushort4 p;
    p.x = f2bf(v.x); p.y = f2bf(v.y); p.z = f2bf(v.z); p.w = f2bf(v.w);
    ((ushort4*)out)[i] = p;
  }
}

// fp32 [K][N] -> bf16 [N][K] transpose+convert. 32x32 tiles.
__global__ __launch_bounds__(256)
void transpose_bf16_kernel(const float* __restrict__ in, u16* __restrict__ out,
                           int K, int N)
{
  __shared__ float t[32][33];
  int n0 = blockIdx.x * 32, k0 = blockIdx.y * 32;
  int tx = threadIdx.x & 31, ty = threadIdx.x >> 5;
  #pragma unroll
  for (int i = 0; i < 4; i++)
    t[ty + i * 8][tx] = in[(long)(k0 + ty + i * 8) * N + n0 + tx];
  __syncthreads();
  #pragma unroll
  for (int i = 0; i < 4; i++)
    out[(long)(n0 + ty + i * 8) * K + k0 + tx] = f2bf(t[tx][ty + i * 8]);
}

// RoPE in-place on first 32 dims of Q and K (bf16 ws). rot=32, half=16.
__global__ __launch_bounds__(256)
void rope_kernel(u16* __restrict__ Q, u16* __restrict__ K)
{
  int idx = blockIdx.x * 256 + threadIdx.x;
  int i = idx & 15;
  int s = (idx >> 4) & 2047;
  int head = (idx >> 15) & 15;
  u16* buf = (idx >> 19) ? K : Q;
  long base = ((long)head * 2048 + s) * 128;
  float inv_freq = exp2f(-(float)i * 0.83048202372184058696f); // 10000^(-i/16)
  float ang = (float)s * inv_freq;
  float c = cosf(ang), sn = sinf(ang);
  float x1 = bf2f(buf[base + i]);
  float x2 = bf2f(buf[base + i + 16]);
  buf[base + i]      = f2bf(x1 * c - x2 * sn);
  buf[base + i + 16] = f2bf(x2 * c + x1 * sn);
}

extern "C" void kernel_launch(void* const* d_in, const int* in_sizes, int n_in,
                              void* d_out, int out_size, void* d_ws, size_t ws_size,
                              hipStream_t stream)
{
  const float* hidden = (const float*)d_in[0];   // [2048][2048] f32
  const float* Wqkv   = (const float*)d_in[1];   // [2048][6144] f32
  const float* bqkv   = (const float*)d_in[2];   // [6144] f32
  const float* Wd     = (const float*)d_in[3];   // [2048][2048] f32
  const float* bd     = (const float*)d_in[4];   // [2048] f32
  float* out = (float*)d_out;                    // [2048][2048] f32

  char* ws = (char*)d_ws;
  u16* Q   = (u16*)(ws);                      //  8 MB  [16][2048][128] bf16
  u16* Kb  = (u16*)(ws + (8ull  << 20));      //  8 MB  [16][2048][128]
  u16* Vt  = (u16*)(ws + (16ull << 20));      //  8 MB  [16][128][2048]
  u16* ctx = (u16*)(ws + (24ull << 20));      //  8 MB  [2048][2048]
  char* regA = ws + (32ull << 20);            // overlay region

  const bool fast = ws_size >= (64ull << 20);

  if (fast) {
    u16* hidden_bf = (u16*)(regA);                  // 8 MB, then Wd_t
    u16* Wqkv_t    = (u16*)(regA + (8ull << 20));   // 24 MB
    u16* Wd_t      = (u16*)(regA);

    convert_bf16_kernel<<<dim3(4096), 256, 0, stream>>>(hidden, hidden_bf, 1048576);
    transpose_bf16_kernel<<<dim3(192, 64), 256, 0, stream>>>(Wqkv, Wqkv_t, 2048, 6144);

    gemm_kernel<<<dim3(48, 16, 1), 256, 0, stream>>>(
        hidden_bf, Wqkv_t, 2048, 2048, 2048, 0, 0, /*mode*/0, 0, 0, 0, bqkv,
        Q, Kb, Vt, nullptr);

    rope_kernel<<<dim3(4096), 256, 0, stream>>>(Q, Kb);
    transpose_bf16_kernel<<<dim3(64, 64), 256, 0, stream>>>(Wd, Wd_t, 2048, 2048);

    flash_kernel<<<dim3(32, 16), 256, 0, stream>>>(Q, Kb, Vt, ctx);

    gemm_kernel<<<dim3(16, 16, 1), 256, 0, stream>>>(
        ctx, Wd_t, 2048, 2048, 2048, 0, 0, /*mode*/3, 0, 0, 0, bd,
        nullptr, nullptr, nullptr, out);
  } else {
    gemm_kernel<<<dim3(48, 16, 1), 256, 0, stream>>>(
        hidden, Wqkv, 2048, 2048, 6144, 0, 0, /*mode*/0, 0, 1, 1, bqkv,
        Q, Kb, Vt, nullptr);
    rope_kernel<<<dim3(4096), 256, 0, stream>>>(Q, Kb);
    flash_kernel<<<dim3(32, 16), 256, 0, stream>>>(Q, Kb, Vt, ctx);
    gemm_kernel<<<dim3(16, 16, 1), 256, 0, stream>>>(
        ctx, Wd, 2048, 2048, 2048, 0, 0, /*mode*/3, 0, 0, 1, bd,
        nullptr, nullptr, nullptr, out);
  }
}

// Round 7
// 388.282 us; speedup vs baseline: 2.4826x; 1.0367x over previous
//
#include <hip/hip_runtime.h>

typedef unsigned short u16;
typedef __attribute__((ext_vector_type(8))) short short8;
typedef __attribute__((ext_vector_type(4))) float floatx4;

#define DEVI static __device__ __forceinline__

DEVI float bf2f(u16 u) {
  union { unsigned u; float f; } x; x.u = ((unsigned)u) << 16; return x.f;
}
DEVI u16 f2bf(float f) {
  union { float f; unsigned u; } x; x.f = f;
  unsigned r = x.u + 0x7fffu + ((x.u >> 16) & 1u);  // RNE
  return (u16)(r >> 16);
}

// async global->LDS, 16 B per lane, wave-uniform LDS base (dest = base + lane*16)
typedef __attribute__((address_space(1))) const void gas_t;
typedef __attribute__((address_space(3))) void las_t;
DEVI void glds16(const void* g, void* l) {
  __builtin_amdgcn_global_load_lds((gas_t*)g, (las_t*)l, 16, 0, 0);
}

#define BM 128
#define BN 128
#define BK 32

// Epilogue modes:
// 0: QKV: +bias, scatter Q(scaled)/K/Vt as bf16
// 3: out(f32) = ctx@Wd + bias
// bf16 path stages via global_load_lds (m97 structure); fp32 fallback keeps
// the VGPR round-trip.
__global__ __launch_bounds__(256)
void gemm_kernel(const void* __restrict__ Av, const void* __restrict__ Bv,
                 int K, int lda, int ldb,
                 long sAz, long sBz, int mode, int head0, int aF32, int bF32,
                 const float* __restrict__ bias,
                 u16* __restrict__ out0, u16* __restrict__ out1,
                 u16* __restrict__ out2, float* __restrict__ outf)
{
  const int bn = blockIdx.x, bm = blockIdx.y, z = blockIdx.z;
  const int m0 = bm * BM, n0 = bn * BN;
  if (mode == 1 && n0 > m0 + (BM - 1)) return;
  int kEnd = K;
  if (mode == 2) { int ke = m0 + BM; kEnd = ke < K ? ke : K; }

  const float* Af = (const float*)Av;
  const u16*   Ab = (const u16*)Av + (long)z * sAz;
  const float* Bf = (const float*)Bv;
  const u16*   Bb = (const u16*)Bv + (long)z * sBz;

  __shared__ __align__(16) u16 As[BM * BK];   // [m][k] bf16
  __shared__ __align__(16) u16 Bs[BN * BK];   // [n][k] bf16

  const int tid  = threadIdx.x;
  const int lane = tid & 63;
  const int wave = tid >> 6;
  const int wm   = (wave & 1) * 64;
  const int wn   = (wave >> 1) * 64;
  const int lr   = lane & 15;
  const int quad = lane >> 4;

  floatx4 acc[4][4];
  #pragma unroll
  for (int i = 0; i < 4; i++)
    #pragma unroll
    for (int j = 0; j < 4; j++)
      acc[i][j] = floatx4{0.f, 0.f, 0.f, 0.f};

  for (int k0 = 0; k0 < kEnd; k0 += BK) {
    __syncthreads();
    if (aF32) {
      #pragma unroll
      for (int L = tid; L < 1024; L += 256) {
        int row = L >> 3, c4 = (L & 7) * 4;
        float4 v = *(const float4*)(Af + (long)(m0 + row) * lda + k0 + c4);
        ushort4 p;
        p.x = f2bf(v.x); p.y = f2bf(v.y); p.z = f2bf(v.z); p.w = f2bf(v.w);
        *(ushort4*)(&As[row * BK + c4]) = p;
      }
    } else {
      // async staging: chunk C -> As u16 offset C*8 (identity), 1024 chunks
      #pragma unroll
      for (int it = 0; it < 4; it++) {
        int Cb = (it * 4 + wave) * 64;          // wave-uniform base chunk
        int C  = Cb + lane;
        int row = C >> 2, c8 = (C & 3) * 8;
        glds16(Ab + (long)(m0 + row) * lda + k0 + c8, &As[Cb * 8]);
      }
    }
    if (bF32) {
      #pragma unroll
      for (int L = tid; L < 1024; L += 256) {
        int kr = L >> 5, n4 = (L & 31) * 4;
        float4 v = *(const float4*)(Bf + (long)(k0 + kr) * ldb + n0 + n4);
        Bs[(n4 + 0) * BK + kr] = f2bf(v.x);
        Bs[(n4 + 1) * BK + kr] = f2bf(v.y);
        Bs[(n4 + 2) * BK + kr] = f2bf(v.z);
        Bs[(n4 + 3) * BK + kr] = f2bf(v.w);
      }
    } else {
      #pragma unroll
      for (int it = 0; it < 4; it++) {
        int Cb = (it * 4 + wave) * 64;
        int C  = Cb + lane;
        int row = C >> 2, c8 = (C & 3) * 8;
        glds16(Bb + (long)(n0 + row) * ldb + k0 + c8, &Bs[Cb * 8]);
      }
    }
    __syncthreads();

    short8 af[4], bf[4];
    #pragma unroll
    for (int i = 0; i < 4; i++)
      af[i] = *(const short8*)(&As[(wm + i * 16 + lr) * BK + quad * 8]);
    #pragma unroll
    for (int j = 0; j < 4; j++)
      bf[j] = *(const short8*)(&Bs[(wn + j * 16 + lr) * BK + quad * 8]);
    #pragma unroll
    for (int i = 0; i < 4; i++)
      #pragma unroll
      for (int j = 0; j < 4; j++)
        acc[i][j] = __builtin_amdgcn_mfma_f32_16x16x32_bf16(af[i], bf[j], acc[i][j], 0, 0, 0);
  }

  #pragma unroll
  for (int i = 0; i < 4; i++) {
    #pragma unroll
    for (int j = 0; j < 4; j++) {
      #pragma unroll
      for (int r = 0; r < 4; r++) {
        int row = m0 + wm + i * 16 + quad * 4 + r;
        int col = n0 + wn + j * 16 + lr;
        float v = acc[i][j][r];
        if (mode == 0) {
          v += bias[col];
          int head = col / 384;
          int w = col - head * 384;
          long hbase = (long)head * 2048 * 128;
          if (w < 128) {        // Q, pre-scaled by 1/sqrt(128)
            out0[hbase + (long)row * 128 + w] = f2bf(v * 0.08838834764831845f);
          } else if (w < 256) { // K
            out1[hbase + (long)row * 128 + (w - 128)] = f2bf(v);
          } else {              // V -> Vt[head][d][t]
            out2[hbase + (long)(w - 256) * 2048 + row] = f2bf(v);
          }
        } else if (mode == 1) {
          out0[((long)z * 2048 + row) * 2048 + col] = f2bf(v);
        } else if (mode == 2) {
          out0[(long)row * 2048 + (head0 + z) * 128 + col] = f2bf(v);
        } else {
          outf[(long)row * 2048 + col] = v + bias[col];
        }
      }
    }
  }
}

// ---------------- fused flash attention, v3 ----------------
// grid (32 slots, 16 heads); qb = head<8 ? slot : 31-slot. Wave wv owns Q
// rows [qb*64+wv*16, +16): softmax wave-local in registers. BN=64 K-tiles;
// LDS = K 16KB + V 16KB = 32 KB. P (16x68/wave) overlays dead K buffer.
__global__ __launch_bounds__(256, 2)
void flash_kernel(const u16* __restrict__ Qg, const u16* __restrict__ Kg,
                  const u16* __restrict__ Vg, u16* __restrict__ ctx)
{
  const int slot = blockIdx.x, head = blockIdx.y;
  const int qb   = (head < 8) ? slot : 31 - slot;
  const int nkt  = qb + 1;               // 64-col K tiles
  const long HS  = 2048L * 128;
  const u16* Qh = Qg + (long)head * HS;
  const u16* Kh = Kg + (long)head * HS;
  const u16* Vh = Vg + (long)head * HS;  // Vt layout [d][t]

  __shared__ __align__(16) u16 k_s[4 * 64 * 32];   // 16 KB  K [kt][n][32]; P overlays
  __shared__ __align__(16) u16 v_s[2 * 128 * 32];  // 16 KB  V [kt2][d][32]

  const int tid  = threadIdx.x;
  const int lane = tid & 63, wv = tid >> 6;
  const int lr   = lane & 15, quad = lane >> 4;
  const int qs   = qb * 64 + wv * 16;    // this wave's strip start row

  short8 qf[4];
  #pragma unroll
  for (int kt = 0; kt < 4; kt++)
    qf[kt] = *(const short8*)(Qh + (long)(qs + lr) * 128 + kt * 32 + quad * 8);

  float m_r[4], l_r[4];
  #pragma unroll
  for (int r = 0; r < 4; r++) { m_r[r] = -1e30f; l_r[r] = 0.f; }

  floatx4 o[8];
  #pragma unroll
  for (int j = 0; j < 8; j++) o[j] = floatx4{0.f, 0.f, 0.f, 0.f};

  const int pbase = wv * 1088;           // P strip: 16 rows x stride 68 u16

  for (int kb = 0; kb < nkt; kb++) {
    __syncthreads();                     // b_A: prev PV reads done
    #pragma unroll
    for (int it = 0; it < 4; it++) {
      int C = it * 256 + tid;
      {
        int kt = C >> 8, n = (C >> 2) & 63, c8 = (C & 3) * 8;
        uint4 x = *(const uint4*)(Kh + (long)(kb * 64 + n) * 128 + kt * 32 + c8);
        *(uint4*)(&k_s[C * 8]) = x;
      }
      {
        int kt2 = C >> 9, d = (C >> 2) & 127, t8 = (C & 3) * 8;
        uint4 x = *(const uint4*)(Vh + (long)d * 2048 + kb * 64 + kt2 * 32 + t8);
        *(uint4*)(&v_s[C * 8]) = x;
      }
    }
    __syncthreads();                     // b_B: staging visible

    floatx4 sa[4];
    #pragma unroll
    for (int j = 0; j < 4; j++) sa[j] = floatx4{0.f, 0.f, 0.f, 0.f};
    #pragma unroll
    for (int kt = 0; kt < 4; kt++) {
      #pragma unroll
      for (int j = 0; j < 4; j++) {
        short8 bf = *(const short8*)(&k_s[kt * 2048 + (j * 16 + lr) * 32 + quad * 8]);
        sa[j] = __builtin_amdgcn_mfma_f32_16x16x32_bf16(qf[kt], bf, sa[j], 0, 0, 0);
      }
    }

    if (kb == nkt - 1) {
      #pragma unroll
      for (int j = 0; j < 4; j++)
        #pragma unroll
        for (int r = 0; r < 4; r++) {
          int cg = kb * 64 + j * 16 + lr;
          int rg = qs + quad * 4 + r;
          if (cg > rg) sa[j][r] = -1e30f;
        }
    }

    float al[4];
    #pragma unroll
    for (int r = 0; r < 4; r++) {
      float v = fmaxf(fmaxf(sa[0][r], sa[1][r]), fmaxf(sa[2][r], sa[3][r]));
      v = fmaxf(v, __shfl_xor(v, 1, 16));
      v = fmaxf(v, __shfl_xor(v, 2, 16));
      v = fmaxf(v, __shfl_xor(v, 4, 16));
      v = fmaxf(v, __shfl_xor(v, 8, 16));
      float nm = fmaxf(m_r[r], v);
      al[r] = __expf(m_r[r] - nm);
      m_r[r] = nm;
    }

    __syncthreads();                     // b_C: K reads done (P overlay next)

    #pragma unroll
    for (int r = 0; r < 4; r++) {
      float s0 = 0.f;
      #pragma unroll
      for (int j = 0; j < 4; j++) {
        float e = __expf(sa[j][r] - m_r[r]);
        k_s[pbase + (quad * 4 + r) * 68 + j * 16 + lr] = f2bf(e);
        s0 += e;
      }
      s0 += __shfl_xor(s0, 1, 16);
      s0 += __shfl_xor(s0, 2, 16);
      s0 += __shfl_xor(s0, 4, 16);
      s0 += __shfl_xor(s0, 8, 16);
      l_r[r] = l_r[r] * al[r] + s0;
    }

    #pragma unroll
    for (int j = 0; j < 8; j++)
      #pragma unroll
      for (int r = 0; r < 4; r++)
        o[j][r] *= al[r];

    #pragma unroll
    for (int kt2 = 0; kt2 < 2; kt2++) {
      short8 pa = *(const short8*)(&k_s[pbase + lr * 68 + kt2 * 32 + quad * 8]);
      #pragma unroll
      for (int j = 0; j < 8; j++) {
        short8 vb = *(const short8*)(&v_s[kt2 * 4096 + (j * 16 + lr) * 32 + quad * 8]);
        o[j] = __builtin_amdgcn_mfma_f32_16x16x32_bf16(pa, vb, o[j], 0, 0, 0);
      }
    }
  } // kb

  #pragma unroll
  for (int r = 0; r < 4; r++) {
    float inv = 1.f / l_r[r];
    int row = qs + quad * 4 + r;
    #pragma unroll
    for (int j = 0; j < 8; j++)
      ctx[(long)row * 2048 + head * 128 + j * 16 + lr] = f2bf(o[j][r] * inv);
  }
}

// fp32 -> bf16 same-layout convert, float4/thread
__global__ __launch_bounds__(256)
void convert_bf16_kernel(const float* __restrict__ in, u16* __restrict__ out, long n4)
{
  long i = (long)blockIdx.x * 256 + threadIdx.x;
  if (i < n4) {
    float4 v = ((const float4*)in)[i];
    ushort4 p;
    p.x = f2bf(v.x); p.y = f2bf(v.y); p.z = f2bf(v.z); p.w = f2bf(v.w);
    ((ushort4*)out)[i] = p;
  }
}

// fp32 [K][N] -> bf16 [N][K] transpose+convert. 32x32 tiles.
__global__ __launch_bounds__(256)
void transpose_bf16_kernel(const float* __restrict__ in, u16* __restrict__ out,
                           int K, int N)
{
  __shared__ float t[32][33];
  int n0 = blockIdx.x * 32, k0 = blockIdx.y * 32;
  int tx = threadIdx.x & 31, ty = threadIdx.x >> 5;
  #pragma unroll
  for (int i = 0; i < 4; i++)
    t[ty + i * 8][tx] = in[(long)(k0 + ty + i * 8) * N + n0 + tx];
  __syncthreads();
  #pragma unroll
  for (int i = 0; i < 4; i++)
    out[(long)(n0 + ty + i * 8) * K + k0 + tx] = f2bf(t[tx][ty + i * 8]);
}

// RoPE in-place on first 32 dims of Q and K (bf16 ws). rot=32, half=16.
__global__ __launch_bounds__(256)
void rope_kernel(u16* __restrict__ Q, u16* __restrict__ K)
{
  int idx = blockIdx.x * 256 + threadIdx.x;
  int i = idx & 15;
  int s = (idx >> 4) & 2047;
  int head = (idx >> 15) & 15;
  u16* buf = (idx >> 19) ? K : Q;
  long base = ((long)head * 2048 + s) * 128;
  float inv_freq = exp2f(-(float)i * 0.83048202372184058696f); // 10000^(-i/16)
  float ang = (float)s * inv_freq;
  float c = cosf(ang), sn = sinf(ang);
  float x1 = bf2f(buf[base + i]);
  float x2 = bf2f(buf[base + i + 16]);
  buf[base + i]      = f2bf(x1 * c - x2 * sn);
  buf[base + i + 16] = f2bf(x2 * c + x1 * sn);
}

extern "C" void kernel_launch(void* const* d_in, const int* in_sizes, int n_in,
                              void* d_out, int out_size, void* d_ws, size_t ws_size,
                              hipStream_t stream)
{
  const float* hidden = (const float*)d_in[0];   // [2048][2048] f32
  const float* Wqkv   = (const float*)d_in[1];   // [2048][6144] f32
  const float* bqkv   = (const float*)d_in[2];   // [6144] f32
  const float* Wd     = (const float*)d_in[3];   // [2048][2048] f32
  const float* bd     = (const float*)d_in[4];   // [2048] f32
  float* out = (float*)d_out;                    // [2048][2048] f32

  char* ws = (char*)d_ws;
  u16* Q   = (u16*)(ws);                      //  8 MB  [16][2048][128] bf16
  u16* Kb  = (u16*)(ws + (8ull  << 20));      //  8 MB  [16][2048][128]
  u16* Vt  = (u16*)(ws + (16ull << 20));      //  8 MB  [16][128][2048]
  u16* ctx = (u16*)(ws + (24ull << 20));      //  8 MB  [2048][2048]
  char* regA = ws + (32ull << 20);            // overlay region

  const bool fast = ws_size >= (64ull << 20);

  if (fast) {
    u16* hidden_bf = (u16*)(regA);                  // 8 MB, then Wd_t
    u16* Wqkv_t    = (u16*)(regA + (8ull << 20));   // 24 MB
    u16* Wd_t      = (u16*)(regA);

    convert_bf16_kernel<<<dim3(4096), 256, 0, stream>>>(hidden, hidden_bf, 1048576);
    transpose_bf16_kernel<<<dim3(192, 64), 256, 0, stream>>>(Wqkv, Wqkv_t, 2048, 6144);

    gemm_kernel<<<dim3(48, 16, 1), 256, 0, stream>>>(
        hidden_bf, Wqkv_t, 2048, 2048, 2048, 0, 0, /*mode*/0, 0, 0, 0, bqkv,
        Q, Kb, Vt, nullptr);

    rope_kernel<<<dim3(4096), 256, 0, stream>>>(Q, Kb);
    transpose_bf16_kernel<<<dim3(64, 64), 256, 0, stream>>>(Wd, Wd_t, 2048, 2048);

    flash_kernel<<<dim3(32, 16), 256, 0, stream>>>(Q, Kb, Vt, ctx);

    gemm_kernel<<<dim3(16, 16, 1), 256, 0, stream>>>(
        ctx, Wd_t, 2048, 2048, 2048, 0, 0, /*mode*/3, 0, 0, 0, bd,
        nullptr, nullptr, nullptr, out);
  } else {
    gemm_kernel<<<dim3(48, 16, 1), 256, 0, stream>>>(
        hidden, Wqkv, 2048, 2048, 6144, 0, 0, /*mode*/0, 0, 1, 1, bqkv,
        Q, Kb, Vt, nullptr);
    rope_kernel<<<dim3(4096), 256, 0, stream>>>(Q, Kb);
    flash_kernel<<<dim3(32, 16), 256, 0, stream>>>(Q, Kb, Vt, ctx);
    gemm_kernel<<<dim3(16, 16, 1), 256, 0, stream>>>(
        ctx, Wd, 2048, 2048, 2048, 0, 0, /*mode*/3, 0, 0, 1, bd,
        nullptr, nullptr, nullptr, out);
  }
}

// Round 8
// 324.577 us; speedup vs baseline: 2.9699x; 1.1963x over previous
//
#include <hip/hip_runtime.h>

typedef unsigned short u16;
typedef __attribute__((ext_vector_type(8))) short short8;
typedef __attribute__((ext_vector_type(4))) float floatx4;

#define DEVI static __device__ __forceinline__

DEVI float bf2f(u16 u) {
  union { unsigned u; float f; } x; x.u = ((unsigned)u) << 16; return x.f;
}
DEVI u16 f2bf(float f) {
  union { float f; unsigned u; } x; x.f = f;
  unsigned r = x.u + 0x7fffu + ((x.u >> 16) & 1u);  // RNE
  return (u16)(r >> 16);
}

// async global->LDS, 16 B per lane, wave-uniform LDS base (dest = base + lane*16)
typedef __attribute__((address_space(1))) const void gas_t;
typedef __attribute__((address_space(3))) void las_t;
DEVI void glds16(const void* g, void* l) {
  __builtin_amdgcn_global_load_lds((gas_t*)g, (las_t*)l, 16, 0, 0);
}

#define BM 128
#define BN 128
#define BK 32

// Panel layout for bf16 GEMM operands: tile (rb, kb) of a [R][K] matrix is
// stored contiguous 128x32 row-major at offset ((rb*(K/32))+kb)*4096 u16.
// Identical to the LDS tile layout -> staging is pure contiguous 1KB bursts.

// Epilogue modes:
// 0: QKV: +bias, scatter Q(scaled)/K/Vt as bf16
// 3: out(f32) = ctx@Wd + bias
// bf16 path: A,B are panel-packed, staged via global_load_lds.
// fp32 fallback (aF32/bF32): row-major via VGPR round-trip.
__global__ __launch_bounds__(256)
void gemm_kernel(const void* __restrict__ Av, const void* __restrict__ Bv,
                 int K, int lda, int ldb,
                 long sAz, long sBz, int mode, int head0, int aF32, int bF32,
                 const float* __restrict__ bias,
                 u16* __restrict__ out0, u16* __restrict__ out1,
                 u16* __restrict__ out2, float* __restrict__ outf)
{
  const int bn = blockIdx.x, bm = blockIdx.y, z = blockIdx.z;
  const int m0 = bm * BM, n0 = bn * BN;
  const int nkb = K >> 5;

  const float* Af = (const float*)Av;
  const u16*   Ab = (const u16*)Av + (long)z * sAz;
  const float* Bf = (const float*)Bv;
  const u16*   Bb = (const u16*)Bv + (long)z * sBz;

  __shared__ __align__(16) u16 As[BM * BK];   // [m][k] bf16
  __shared__ __align__(16) u16 Bs[BN * BK];   // [n][k] bf16

  const int tid  = threadIdx.x;
  const int lane = tid & 63;
  const int wave = tid >> 6;
  const int wm   = (wave & 1) * 64;
  const int wn   = (wave >> 1) * 64;
  const int lr   = lane & 15;
  const int quad = lane >> 4;

  floatx4 acc[4][4];
  #pragma unroll
  for (int i = 0; i < 4; i++)
    #pragma unroll
    for (int j = 0; j < 4; j++)
      acc[i][j] = floatx4{0.f, 0.f, 0.f, 0.f};

  for (int kb = 0; kb < nkb; kb++) {
    const int k0 = kb * BK;
    __syncthreads();
    if (aF32) {
      #pragma unroll
      for (int L = tid; L < 1024; L += 256) {
        int row = L >> 3, c4 = (L & 7) * 4;
        float4 v = *(const float4*)(Af + (long)(m0 + row) * lda + k0 + c4);
        ushort4 p;
        p.x = f2bf(v.x); p.y = f2bf(v.y); p.z = f2bf(v.z); p.w = f2bf(v.w);
        *(ushort4*)(&As[row * BK + c4]) = p;
      }
    } else {
      // panel A: contiguous 8KB tile; chunk (Cb+lane) -> As u16 (Cb+lane)*8
      const u16* At = Ab + ((long)bm * nkb + kb) * 4096;
      #pragma unroll
      for (int it = 0; it < 2; it++) {
        int Cb = (wave * 2 + it) * 64;
        glds16(At + (long)(Cb + lane) * 8, &As[Cb * 8]);
      }
    }
    if (bF32) {
      #pragma unroll
      for (int L = tid; L < 1024; L += 256) {
        int kr = L >> 5, n4 = (L & 31) * 4;
        float4 v = *(const float4*)(Bf + (long)(k0 + kr) * ldb + n0 + n4);
        Bs[(n4 + 0) * BK + kr] = f2bf(v.x);
        Bs[(n4 + 1) * BK + kr] = f2bf(v.y);
        Bs[(n4 + 2) * BK + kr] = f2bf(v.z);
        Bs[(n4 + 3) * BK + kr] = f2bf(v.w);
      }
    } else {
      const u16* Bt = Bb + ((long)bn * nkb + kb) * 4096;
      #pragma unroll
      for (int it = 0; it < 2; it++) {
        int Cb = (wave * 2 + it) * 64;
        glds16(Bt + (long)(Cb + lane) * 8, &Bs[Cb * 8]);
      }
    }
    __syncthreads();

    short8 af[4], bf[4];
    #pragma unroll
    for (int i = 0; i < 4; i++)
      af[i] = *(const short8*)(&As[(wm + i * 16 + lr) * BK + quad * 8]);
    #pragma unroll
    for (int j = 0; j < 4; j++)
      bf[j] = *(const short8*)(&Bs[(wn + j * 16 + lr) * BK + quad * 8]);
    #pragma unroll
    for (int i = 0; i < 4; i++)
      #pragma unroll
      for (int j = 0; j < 4; j++)
        acc[i][j] = __builtin_amdgcn_mfma_f32_16x16x32_bf16(af[i], bf[j], acc[i][j], 0, 0, 0);
  }

  #pragma unroll
  for (int i = 0; i < 4; i++) {
    #pragma unroll
    for (int j = 0; j < 4; j++) {
      #pragma unroll
      for (int r = 0; r < 4; r++) {
        int row = m0 + wm + i * 16 + quad * 4 + r;
        int col = n0 + wn + j * 16 + lr;
        float v = acc[i][j][r];
        if (mode == 0) {
          v += bias[col];
          int head = col / 384;
          int w = col - head * 384;
          long hbase = (long)head * 2048 * 128;
          if (w < 128) {        // Q, pre-scaled by 1/sqrt(128)
            out0[hbase + (long)row * 128 + w] = f2bf(v * 0.08838834764831845f);
          } else if (w < 256) { // K
            out1[hbase + (long)row * 128 + (w - 128)] = f2bf(v);
          } else {              // V -> Vt[head][d][t]
            out2[hbase + (long)(w - 256) * 2048 + row] = f2bf(v);
          }
        } else {
          outf[(long)row * 2048 + col] = v + bias[col];
        }
      }
    }
  }
}

// ---------------- fused flash attention, v3 ----------------
// grid (32 slots, 16 heads); qb = head<8 ? slot : 31-slot. Wave wv owns Q
// rows [qb*64+wv*16, +16): softmax wave-local in registers. BN=64 K-tiles;
// LDS = K 16KB + V 16KB = 32 KB. P (16x68/wave) overlays dead K buffer.
// ctx written in panel layout (A-operand of the dense GEMM).
__global__ __launch_bounds__(256, 2)
void flash_kernel(const u16* __restrict__ Qg, const u16* __restrict__ Kg,
                  const u16* __restrict__ Vg, u16* __restrict__ ctx)
{
  const int slot = blockIdx.x, head = blockIdx.y;
  const int qb   = (head < 8) ? slot : 31 - slot;
  const int nkt  = qb + 1;               // 64-col K tiles
  const long HS  = 2048L * 128;
  const u16* Qh = Qg + (long)head * HS;
  const u16* Kh = Kg + (long)head * HS;
  const u16* Vh = Vg + (long)head * HS;  // Vt layout [d][t]

  __shared__ __align__(16) u16 k_s[4 * 64 * 32];   // 16 KB  K [kt][n][32]; P overlays
  __shared__ __align__(16) u16 v_s[2 * 128 * 32];  // 16 KB  V [kt2][d][32]

  const int tid  = threadIdx.x;
  const int lane = tid & 63, wv = tid >> 6;
  const int lr   = lane & 15, quad = lane >> 4;
  const int qs   = qb * 64 + wv * 16;    // this wave's strip start row

  short8 qf[4];
  #pragma unroll
  for (int kt = 0; kt < 4; kt++)
    qf[kt] = *(const short8*)(Qh + (long)(qs + lr) * 128 + kt * 32 + quad * 8);

  float m_r[4], l_r[4];
  #pragma unroll
  for (int r = 0; r < 4; r++) { m_r[r] = -1e30f; l_r[r] = 0.f; }

  floatx4 o[8];
  #pragma unroll
  for (int j = 0; j < 8; j++) o[j] = floatx4{0.f, 0.f, 0.f, 0.f};

  const int pbase = wv * 1088;           // P strip: 16 rows x stride 68 u16

  for (int kb = 0; kb < nkt; kb++) {
    __syncthreads();                     // b_A: prev PV reads done
    #pragma unroll
    for (int it = 0; it < 4; it++) {
      int C = it * 256 + tid;
      {
        int kt = C >> 8, n = (C >> 2) & 63, c8 = (C & 3) * 8;
        uint4 x = *(const uint4*)(Kh + (long)(kb * 64 + n) * 128 + kt * 32 + c8);
        *(uint4*)(&k_s[C * 8]) = x;
      }
      {
        int kt2 = C >> 9, d = (C >> 2) & 127, t8 = (C & 3) * 8;
        uint4 x = *(const uint4*)(Vh + (long)d * 2048 + kb * 64 + kt2 * 32 + t8);
        *(uint4*)(&v_s[C * 8]) = x;
      }
    }
    __syncthreads();                     // b_B: staging visible

    floatx4 sa[4];
    #pragma unroll
    for (int j = 0; j < 4; j++) sa[j] = floatx4{0.f, 0.f, 0.f, 0.f};
    #pragma unroll
    for (int kt = 0; kt < 4; kt++) {
      #pragma unroll
      for (int j = 0; j < 4; j++) {
        short8 bf = *(const short8*)(&k_s[kt * 2048 + (j * 16 + lr) * 32 + quad * 8]);
        sa[j] = __builtin_amdgcn_mfma_f32_16x16x32_bf16(qf[kt], bf, sa[j], 0, 0, 0);
      }
    }

    if (kb == nkt - 1) {
      #pragma unroll
      for (int j = 0; j < 4; j++)
        #pragma unroll
        for (int r = 0; r < 4; r++) {
          int cg = kb * 64 + j * 16 + lr;
          int rg = qs + quad * 4 + r;
          if (cg > rg) sa[j][r] = -1e30f;
        }
    }

    float al[4];
    #pragma unroll
    for (int r = 0; r < 4; r++) {
      float v = fmaxf(fmaxf(sa[0][r], sa[1][r]), fmaxf(sa[2][r], sa[3][r]));
      v = fmaxf(v, __shfl_xor(v, 1, 16));
      v = fmaxf(v, __shfl_xor(v, 2, 16));
      v = fmaxf(v, __shfl_xor(v, 4, 16));
      v = fmaxf(v, __shfl_xor(v, 8, 16));
      float nm = fmaxf(m_r[r], v);
      al[r] = __expf(m_r[r] - nm);
      m_r[r] = nm;
    }

    __syncthreads();                     // b_C: K reads done (P overlay next)

    #pragma unroll
    for (int r = 0; r < 4; r++) {
      float s0 = 0.f;
      #pragma unroll
      for (int j = 0; j < 4; j++) {
        float e = __expf(sa[j][r] - m_r[r]);
        k_s[pbase + (quad * 4 + r) * 68 + j * 16 + lr] = f2bf(e);
        s0 += e;
      }
      s0 += __shfl_xor(s0, 1, 16);
      s0 += __shfl_xor(s0, 2, 16);
      s0 += __shfl_xor(s0, 4, 16);
      s0 += __shfl_xor(s0, 8, 16);
      l_r[r] = l_r[r] * al[r] + s0;
    }

    #pragma unroll
    for (int j = 0; j < 8; j++)
      #pragma unroll
      for (int r = 0; r < 4; r++)
        o[j][r] *= al[r];

    #pragma unroll
    for (int kt2 = 0; kt2 < 2; kt2++) {
      short8 pa = *(const short8*)(&k_s[pbase + lr * 68 + kt2 * 32 + quad * 8]);
      #pragma unroll
      for (int j = 0; j < 8; j++) {
        short8 vb = *(const short8*)(&v_s[kt2 * 4096 + (j * 16 + lr) * 32 + quad * 8]);
        o[j] = __builtin_amdgcn_mfma_f32_16x16x32_bf16(pa, vb, o[j], 0, 0, 0);
      }
    }
  } // kb

  // epilogue -> ctx PANELS: element (row, c), c = head*128 + j*16 + lr.
  // panel = ((row>>7)*64 + (c>>5))*4096 + (row&127)*32 + (c&31)
  #pragma unroll
  for (int r = 0; r < 4; r++) {
    float inv = 1.f / l_r[r];
    int row = qs + quad * 4 + r;
    long prow = ((long)(row >> 7) * 64) * 4096 + (row & 127) * 32;
    #pragma unroll
    for (int j = 0; j < 8; j++) {
      int c = head * 128 + j * 16 + lr;
      ctx[prow + (long)(c >> 5) * 4096 + (c & 31)] = f2bf(o[j][r] * inv);
    }
  }
}

// fp32 [M][K] row-major -> bf16 PANELS. float4/thread.
__global__ __launch_bounds__(256)
void convert_bf16_kernel(const float* __restrict__ in, u16* __restrict__ out,
                         int K, long n4)
{
  long i = (long)blockIdx.x * 256 + threadIdx.x;
  if (i < n4) {
    float4 v = ((const float4*)in)[i];
    ushort4 p;
    p.x = f2bf(v.x); p.y = f2bf(v.y); p.z = f2bf(v.z); p.w = f2bf(v.w);
    long e = i * 4;
    int row = (int)(e / K), k = (int)(e % K);
    long d = ((long)(row >> 7) * (K >> 5) + (k >> 5)) * 4096
           + (row & 127) * 32 + (k & 31);
    *(ushort4*)(&out[d]) = p;
  }
}

// fp32 [K][N] -> bf16 PANELS of the [N][K] transpose. 32x32 tiles.
__global__ __launch_bounds__(256)
void transpose_bf16_kernel(const float* __restrict__ in, u16* __restrict__ out,
                           int K, int N)
{
  __shared__ float t[32][33];
  int n0 = blockIdx.x * 32, k0 = blockIdx.y * 32;
  int tx = threadIdx.x & 31, ty = threadIdx.x >> 5;
  #pragma unroll
  for (int i = 0; i < 4; i++)
    t[ty + i * 8][tx] = in[(long)(k0 + ty + i * 8) * N + n0 + tx];
  __syncthreads();
  const int nkb = K >> 5;
  #pragma unroll
  for (int i = 0; i < 4; i++) {
    int n = n0 + ty + i * 8;
    int k = k0 + tx;
    long d = ((long)(n >> 7) * nkb + (k >> 5)) * 4096 + (n & 127) * 32 + (k & 31);
    out[d] = f2bf(t[tx][ty + i * 8]);
  }
}

// RoPE in-place on first 32 dims of Q and K (bf16 ws). rot=32, half=16.
__global__ __launch_bounds__(256)
void rope_kernel(u16* __restrict__ Q, u16* __restrict__ K)
{
  int idx = blockIdx.x * 256 + threadIdx.x;
  int i = idx & 15;
  int s = (idx >> 4) & 2047;
  int head = (idx >> 15) & 15;
  u16* buf = (idx >> 19) ? K : Q;
  long base = ((long)head * 2048 + s) * 128;
  float inv_freq = exp2f(-(float)i * 0.83048202372184058696f); // 10000^(-i/16)
  float ang = (float)s * inv_freq;
  float c = cosf(ang), sn = sinf(ang);
  float x1 = bf2f(buf[base + i]);
  float x2 = bf2f(buf[base + i + 16]);
  buf[base + i]      = f2bf(x1 * c - x2 * sn);
  buf[base + i + 16] = f2bf(x2 * c + x1 * sn);
}

extern "C" void kernel_launch(void* const* d_in, const int* in_sizes, int n_in,
                              void* d_out, int out_size, void* d_ws, size_t ws_size,
                              hipStream_t stream)
{
  const float* hidden = (const float*)d_in[0];   // [2048][2048] f32
  const float* Wqkv   = (const float*)d_in[1];   // [2048][6144] f32
  const float* bqkv   = (const float*)d_in[2];   // [6144] f32
  const float* Wd     = (const float*)d_in[3];   // [2048][2048] f32
  const float* bd     = (const float*)d_in[4];   // [2048] f32
  float* out = (float*)d_out;                    // [2048][2048] f32

  char* ws = (char*)d_ws;
  u16* Q   = (u16*)(ws);                      //  8 MB  [16][2048][128] bf16
  u16* Kb  = (u16*)(ws + (8ull  << 20));      //  8 MB  [16][2048][128]
  u16* Vt  = (u16*)(ws + (16ull << 20));      //  8 MB  [16][128][2048]
  u16* ctx = (u16*)(ws + (24ull << 20));      //  8 MB  [2048][2048] panels
  char* regA = ws + (32ull << 20);            // overlay region

  const bool fast = ws_size >= (64ull << 20);

  if (fast) {
    u16* hidden_bf = (u16*)(regA);                  // 8 MB panels, then Wd_t
    u16* Wqkv_t    = (u16*)(regA + (8ull << 20));   // 24 MB panels
    u16* Wd_t      = (u16*)(regA);                  // 8 MB panels

    convert_bf16_kernel<<<dim3(4096), 256, 0, stream>>>(hidden, hidden_bf, 2048, 1048576);
    transpose_bf16_kernel<<<dim3(192, 64), 256, 0, stream>>>(Wqkv, Wqkv_t, 2048, 6144);

    gemm_kernel<<<dim3(48, 16, 1), 256, 0, stream>>>(
        hidden_bf, Wqkv_t, 2048, 2048, 2048, 0, 0, /*mode*/0, 0, 0, 0, bqkv,
        Q, Kb, Vt, nullptr);

    rope_kernel<<<dim3(4096), 256, 0, stream>>>(Q, Kb);
    transpose_bf16_kernel<<<dim3(64, 64), 256, 0, stream>>>(Wd, Wd_t, 2048, 2048);

    flash_kernel<<<dim3(32, 16), 256, 0, stream>>>(Q, Kb, Vt, ctx);

    gemm_kernel<<<dim3(16, 16, 1), 256, 0, stream>>>(
        ctx, Wd_t, 2048, 2048, 2048, 0, 0, /*mode*/3, 0, 0, 0, bd,
        nullptr, nullptr, nullptr, out);
  } else {
    // fallback: fp32 in-GEMM staging for QKV; dense uses ctx panels + fp32 Wd
    gemm_kernel<<<dim3(48, 16, 1), 256, 0, stream>>>(
        hidden, Wqkv, 2048, 2048, 6144, 0, 0, /*mode*/0, 0, 1, 1, bqkv,
        Q, Kb, Vt, nullptr);
    rope_kernel<<<dim3(4096), 256, 0, stream>>>(Q, Kb);
    flash_kernel<<<dim3(32, 16), 256, 0, stream>>>(Q, Kb, Vt, ctx);
    gemm_kernel<<<dim3(16, 16, 1), 256, 0, stream>>>(
        ctx, Wd, 2048, 2048, 2048, 0, 0, /*mode*/3, 0, 0, 1, bd,
        nullptr, nullptr, nullptr, out);
  }
}